// Round 10
// baseline (480.119 us; speedup 1.0000x reference)
//
#include <hip/hip_runtime.h>
#include <stdint.h>

typedef unsigned int uint;
typedef short bf16x8 __attribute__((ext_vector_type(8)));
typedef float f32x4 __attribute__((ext_vector_type(4)));

#define EPS 1e-5f

// Shapes: B=16, Cin=128, Cout=256, T=512, H=W=64, HW=4096, NPIX=65536

// ---------------- BN1 stats ----------------
__global__ __launch_bounds__(256) void k_bn1_part(const float* __restrict__ x, float* __restrict__ part) {
  int c = blockIdx.x, chunk = blockIdx.y;
  float s = 0.f, s2 = 0.f;
  #pragma unroll
  for (int jb = 0; jb < 2; ++jb) {
    int b = chunk * 2 + jb;
    const float4* xb = (const float4*)(x + (((size_t)((b << 7) | c)) << 12));
    #pragma unroll
    for (int k = 0; k < 4; ++k) {
      float4 q = xb[k * 256 + threadIdx.x];
      s += (q.x + q.y) + (q.z + q.w);
      s2 += q.x * q.x + q.y * q.y + q.z * q.z + q.w * q.w;
    }
  }
  #pragma unroll
  for (int off = 32; off > 0; off >>= 1) { s += __shfl_down(s, off); s2 += __shfl_down(s2, off); }
  __shared__ float ls[4], ls2[4];
  int wid = threadIdx.x >> 6, lane = threadIdx.x & 63;
  if (lane == 0) { ls[wid] = s; ls2[wid] = s2; }
  __syncthreads();
  if (threadIdx.x == 0) {
    part[(c * 8 + chunk) * 2 + 0] = ls[0] + ls[1] + ls[2] + ls[3];
    part[(c * 8 + chunk) * 2 + 1] = ls2[0] + ls2[1] + ls2[2] + ls2[3];
  }
}

__global__ void k_bn1_fin(const float* __restrict__ part, const float* __restrict__ g,
                          const float* __restrict__ be, float* __restrict__ sc, float* __restrict__ sh) {
  int c = threadIdx.x;
  float s = 0.f, s2 = 0.f;
  for (int k = 0; k < 8; ++k) { s += part[(c * 8 + k) * 2]; s2 += part[(c * 8 + k) * 2 + 1]; }
  const float inv = 1.f / 65536.f;
  float m = s * inv, var = s2 * inv - m * m;
  float rs = rsqrtf(var + EPS);
  float scale = rs * g[c];
  sc[c] = scale;
  sh[c] = be[c] - m * scale;
}

// ---------------- weight packing ----------------
__global__ __launch_bounds__(128) void k_packw1(const float* __restrict__ w1, uint* __restrict__ wb,
                                                float* __restrict__ alpha) {
  int co = blockIdx.x, wid = threadIdx.x >> 6, lane = threadIdx.x & 63;
  const float* wp = w1 + (co * 128 + threadIdx.x) * 9;
  float wv[9]; float s = 0.f;
  #pragma unroll
  for (int tp = 0; tp < 9; ++tp) { wv[tp] = wp[tp]; s += fabsf(wv[tp]); }
  #pragma unroll
  for (int tp = 0; tp < 9; ++tp) {
    unsigned long long m = __ballot(wv[tp] > 0.f);
    if (lane == 0) {
      wb[(co * 9 + tp) * 4 + wid * 2 + 0] = (uint)m;
      wb[(co * 9 + tp) * 4 + wid * 2 + 1] = (uint)(m >> 32);
    }
  }
  #pragma unroll
  for (int off = 32; off > 0; off >>= 1) s += __shfl_down(s, off);
  __shared__ float l2[2];
  if (lane == 0) l2[wid] = s;
  __syncthreads();
  if (threadIdx.x == 0) alpha[co] = (l2[0] + l2[1]) * (1.f / 1152.f);
}

// emits bf16 sign weights TRANSPOSED for MFMA: wT[slice=(tap*8+chunk*4+kc)][co][32ci_local]
__global__ __launch_bounds__(256) void k_packw2(const float* __restrict__ w2, uint* __restrict__ wb,
                                                float* __restrict__ alpha, ushort* __restrict__ wT) {
  int co = blockIdx.x, wid = threadIdx.x >> 6, lane = threadIdx.x & 63;
  int ci = threadIdx.x;
  const float* wp = w2 + (co * 256 + ci) * 9;
  float wv[9]; float s = 0.f;
  #pragma unroll
  for (int tp = 0; tp < 9; ++tp) { wv[tp] = wp[tp]; s += fabsf(wv[tp]); }
  int chunk = ci >> 7, kc = (ci >> 5) & 3, cil = ci & 31;
  #pragma unroll
  for (int tp = 0; tp < 9; ++tp) {
    wT[(((tp << 3) + (chunk << 2) + kc) << 13) + (co << 5) + cil] = (wv[tp] > 0.f) ? 0x3F80u : 0xBF80u;
    unsigned long long m = __ballot(wv[tp] > 0.f);
    if (lane == 0) {
      wb[(co * 9 + tp) * 8 + wid * 2 + 0] = (uint)m;
      wb[(co * 9 + tp) * 8 + wid * 2 + 1] = (uint)(m >> 32);
    }
  }
  #pragma unroll
  for (int off = 32; off > 0; off >>= 1) s += __shfl_down(s, off);
  __shared__ float l4[4];
  if (lane == 0) l4[wid] = s;
  __syncthreads();
  if (threadIdx.x == 0) alpha[co] = (l4[0] + l4[1] + l4[2] + l4[3]) * (1.f / 2304.f);
}

__global__ __launch_bounds__(256) void k_base(const uint* __restrict__ wb1, const uint* __restrict__ wb2,
                                              int* __restrict__ base1, int* __restrict__ base2) {
  int co = threadIdx.x;
  int pc1[9], pc2[9];
  #pragma unroll
  for (int tp = 0; tp < 9; ++tp) {
    uint a = 0;
    #pragma unroll
    for (int k = 0; k < 4; ++k) a += __popc(wb1[co * 36 + tp * 4 + k]);
    pc1[tp] = (int)a;
    uint b = 0;
    #pragma unroll
    for (int k = 0; k < 8; ++k) b += __popc(wb2[co * 72 + tp * 8 + k]);
    pc2[tp] = (int)b;
  }
  #pragma unroll
  for (int pat = 0; pat < 9; ++pat) {
    int yt = pat / 3, xt = pat % 3;
    int b1v = 1152, b2v = 2304;
    #pragma unroll
    for (int tp = 0; tp < 9; ++tp) {
      int dy = tp / 3 - 1, dx = tp % 3 - 1;
      bool inv = (dy < 0 && yt == 0) || (dy > 0 && yt == 2) || (dx < 0 && xt == 0) || (dx > 0 && xt == 2);
      if (inv) { b1v -= 128 - 2 * pc1[tp]; b2v -= 256 - 2 * pc2[tp]; }
    }
    base1[pat * 256 + co] = b1v;
    base2[pat * 256 + co] = b2v;
  }
}

__global__ __launch_bounds__(128) void k_packws(const float* __restrict__ wsk, float* __restrict__ swT) {
  int co = blockIdx.x, ci = threadIdx.x;
  float v = wsk[co * 128 + ci];
  float s = fabsf(v);
  #pragma unroll
  for (int off = 32; off > 0; off >>= 1) s += __shfl_down(s, off);
  __shared__ float l2[2]; __shared__ float tot;
  int wid = threadIdx.x >> 6, lane = threadIdx.x & 63;
  if (lane == 0) l2[wid] = s;
  __syncthreads();
  if (threadIdx.x == 0) tot = (l2[0] + l2[1]) * (1.f / 128.f);
  __syncthreads();
  float a = tot;
  swT[ci * 256 + co] = (v > 0.f) ? a : -a;
}

// ---------------- temb ----------------
__global__ __launch_bounds__(256) void k_temb(const float* __restrict__ t, const float* __restrict__ tW,
                                              const float* __restrict__ tbias, float* __restrict__ temb) {
  int b = blockIdx.x, co = threadIdx.x;
  const float* tr = t + b * 512;
  const float* wr = tW + co * 512;
  float a0 = 0, a1 = 0, a2 = 0, a3 = 0;
  #pragma unroll 8
  for (int k = 0; k < 512; k += 4) {
    a0 = fmaf(tr[k + 0], wr[k + 0], a0);
    a1 = fmaf(tr[k + 1], wr[k + 1], a1);
    a2 = fmaf(tr[k + 2], wr[k + 2], a2);
    a3 = fmaf(tr[k + 3], wr[k + 3], a3);
  }
  temb[b * 256 + co] = (a0 + a1) + (a2 + a3) + tbias[co];
}

// ---------------- skip GEMM + fused bin1 ----------------
__global__ __launch_bounds__(256, 2) void k_skip(const float* __restrict__ x, const float* __restrict__ swT,
                                                 const float* __restrict__ bsk, const float* __restrict__ b2,
                                                 const float* __restrict__ sc1, const float* __restrict__ sh1,
                                                 uint* __restrict__ sbinw, float* __restrict__ out) {
  __shared__ float xs[128 * 64];
  __shared__ float wsl[128 * 64];
  int g = blockIdx.x;
  int b = g >> 6;
  int px0 = (g & 63) << 6;
  int co0 = blockIdx.y << 6;
  int t = threadIdx.x;

  {
    const float* xb = x + ((size_t)(b << 7) << 12) + px0;
    float4* xs4 = (float4*)xs;
    #pragma unroll
    for (int k = 0; k < 8; ++k) {
      int idx = k * 256 + t;
      int ci = idx >> 4, f4 = idx & 15;
      xs4[idx] = *(const float4*)(xb + ((size_t)ci << 12) + (f4 << 2));
    }
  }
  {
    float4* ws4 = (float4*)wsl;
    #pragma unroll
    for (int k = 0; k < 8; ++k) {
      int idx = k * 256 + t;
      int ci = idx >> 4, f4 = idx & 15;
      ws4[idx] = *(const float4*)(swT + ci * 256 + co0 + (f4 << 2));
    }
  }
  __syncthreads();

  if (blockIdx.y == 0) {
    int px = t & 63, wd = t >> 6;
    int ci0 = wd << 5;
    uint acc = 0;
    #pragma unroll
    for (int i = 0; i < 32; ++i) {
      int ci = ci0 + i;
      float v = xs[ci * 64 + px];
      acc |= ((v * sc1[ci] + sh1[ci]) > 0.f ? 1u : 0u) << i;
    }
    sbinw[(((size_t)b << 12) | (px0 + px)) * 4 + wd] = acc;
  }

  int tx = t & 15, ty = t >> 4;
  const float4* xs4 = (const float4*)xs;
  const float4* ws4 = (const float4*)wsl;
  float4 acc0 = make_float4(0, 0, 0, 0), acc1 = acc0, acc2 = acc0, acc3 = acc0;
  #pragma unroll 4
  for (int ci = 0; ci < 128; ++ci) {
    float4 xv = xs4[ci * 16 + tx];
    float4 wv = ws4[ci * 16 + ty];
    acc0.x = fmaf(wv.x, xv.x, acc0.x); acc0.y = fmaf(wv.x, xv.y, acc0.y);
    acc0.z = fmaf(wv.x, xv.z, acc0.z); acc0.w = fmaf(wv.x, xv.w, acc0.w);
    acc1.x = fmaf(wv.y, xv.x, acc1.x); acc1.y = fmaf(wv.y, xv.y, acc1.y);
    acc1.z = fmaf(wv.y, xv.z, acc1.z); acc1.w = fmaf(wv.y, xv.w, acc1.w);
    acc2.x = fmaf(wv.z, xv.x, acc2.x); acc2.y = fmaf(wv.z, xv.y, acc2.y);
    acc2.z = fmaf(wv.z, xv.z, acc2.z); acc2.w = fmaf(wv.z, xv.w, acc2.w);
    acc3.x = fmaf(wv.w, xv.x, acc3.x); acc3.y = fmaf(wv.w, xv.y, acc3.y);
    acc3.z = fmaf(wv.w, xv.z, acc3.z); acc3.w = fmaf(wv.w, xv.w, acc3.w);
  }

  float* op = out + ((size_t)b << 20) + px0 + (tx << 2);
  int cob = co0 + (ty << 2);
  float4 r;
  r = acc0; { float bb = bsk[cob + 0] + b2[cob + 0]; r.x += bb; r.y += bb; r.z += bb; r.w += bb; }
  *(float4*)(op + (size_t)(cob + 0) * 4096) = r;
  r = acc1; { float bb = bsk[cob + 1] + b2[cob + 1]; r.x += bb; r.y += bb; r.z += bb; r.w += bb; }
  *(float4*)(op + (size_t)(cob + 1) * 4096) = r;
  r = acc2; { float bb = bsk[cob + 2] + b2[cob + 2]; r.x += bb; r.y += bb; r.z += bb; r.w += bb; }
  *(float4*)(op + (size_t)(cob + 2) * 4096) = r;
  r = acc3; { float bb = bsk[cob + 3] + b2[cob + 3]; r.x += bb; r.y += bb; r.z += bb; r.w += bb; }
  *(float4*)(op + (size_t)(cob + 3) * 4096) = r;
}

// ---------------- conv1 (popcount, R4-proven) ----------------
__global__ __launch_bounds__(256, 1) void k_conv1(const uint4* __restrict__ sbin, const uint* __restrict__ wb1,
                                                  const int* __restrict__ base1, short* __restrict__ S1) {
  __shared__ uint wlds[32 * 36];
  __shared__ int blds[9 * 32];
  int co0 = blockIdx.y << 5;
  #pragma unroll
  for (int k = 0; k < 4; ++k) wlds[k * 256 + threadIdx.x] = wb1[co0 * 36 + k * 256 + threadIdx.x];
  if (threadIdx.x < 128) wlds[1024 + threadIdx.x] = wb1[co0 * 36 + 1024 + threadIdx.x];
  #pragma unroll
  for (int k = 0; k < 2; ++k) {
    int idx = k * 256 + threadIdx.x;
    if (idx < 288) blds[idx] = base1[(idx >> 5) * 256 + co0 + (idx & 31)];
  }

  int bt = blockIdx.x;
  int b = bt >> 4;
  int y = ((bt & 15) << 2) | (threadIdx.x >> 6);
  int cx = threadIdx.x & 63;
  uint nb[9][4];
  #pragma unroll
  for (int dy = -1; dy <= 1; ++dy)
    #pragma unroll
    for (int dx = -1; dx <= 1; ++dx) {
      int tp = (dy + 1) * 3 + (dx + 1);
      int yy = y + dy, xx = cx + dx;
      bool v = ((unsigned)yy < 64u) && ((unsigned)xx < 64u);
      uint4 q = make_uint4(0, 0, 0, 0);
      if (v) q = sbin[(b << 12) | (yy << 6) | xx];
      nb[tp][0] = q.x; nb[tp][1] = q.y; nb[tp][2] = q.z; nb[tp][3] = q.w;
    }
  int pat = ((y == 0) ? 0 : ((y == 63) ? 6 : 3)) + ((cx == 0) ? 0 : ((cx == 63) ? 2 : 1));
  __syncthreads();

  int p = (y << 6) | cx;
  short* op = S1 + ((size_t)b << 20) + ((size_t)co0 << 12) + p;
  #pragma unroll 1
  for (int cc = 0; cc < 4; ++cc) {
    short accv[8];
    #pragma unroll
    for (int j = 0; j < 8; ++j) {
      int co_l = cc * 8 + j;
      const uint4* wp4 = (const uint4*)(wlds + co_l * 36);
      uint m0 = 0, m1 = 0, m2 = 0, m3 = 0;
      #pragma unroll
      for (int tp = 0; tp < 9; ++tp) {
        uint4 w4 = wp4[tp];
        m0 += __popc(nb[tp][0] ^ w4.x);
        m1 += __popc(nb[tp][1] ^ w4.y);
        m2 += __popc(nb[tp][2] ^ w4.z);
        m3 += __popc(nb[tp][3] ^ w4.w);
      }
      accv[j] = (short)(blds[pat * 32 + co_l] - 2 * (int)((m0 + m1) + (m2 + m3)));
    }
    #pragma unroll
    for (int j = 0; j < 8; ++j) op[(size_t)(cc * 8 + j) << 12] = accv[j];
  }
}

// ---------------- BN2 stats ----------------
__global__ __launch_bounds__(256) void k_bn2_part(const short* __restrict__ S1, const float* __restrict__ al1,
                                                  const float* __restrict__ b1, const float* __restrict__ temb,
                                                  float* __restrict__ part) {
  int co = blockIdx.x, chunk = blockIdx.y;
  float a = al1[co], bb = b1[co];
  float s = 0.f, s2 = 0.f;
  #pragma unroll
  for (int jb = 0; jb < 2; ++jb) {
    int b = chunk * 2 + jb;
    float tb_ = bb + temb[(b << 8) | co];
    const uint4* sp = (const uint4*)(S1 + ((size_t)b << 20) + ((size_t)co << 12));
    #pragma unroll
    for (int k = 0; k < 2; ++k) {
      uint4 q = sp[k * 256 + threadIdx.x];
      uint ws[4] = {q.x, q.y, q.z, q.w};
      #pragma unroll
      for (int w = 0; w < 4; ++w) {
        float f0 = fmaf(a, (float)((short)(ws[w] & 0xffffu)), tb_);
        float f1 = fmaf(a, (float)((short)(ws[w] >> 16)), tb_);
        s += f0 + f1;
        s2 += f0 * f0 + f1 * f1;
      }
    }
  }
  #pragma unroll
  for (int off = 32; off > 0; off >>= 1) { s += __shfl_down(s, off); s2 += __shfl_down(s2, off); }
  __shared__ float ls[4], ls2[4];
  int wid = threadIdx.x >> 6, lane = threadIdx.x & 63;
  if (lane == 0) { ls[wid] = s; ls2[wid] = s2; }
  __syncthreads();
  if (threadIdx.x == 0) {
    part[(co * 8 + chunk) * 2 + 0] = ls[0] + ls[1] + ls[2] + ls[3];
    part[(co * 8 + chunk) * 2 + 1] = ls2[0] + ls2[1] + ls2[2] + ls2[3];
  }
}

__global__ void k_bn2_fin(const float* __restrict__ part, const float* __restrict__ al1,
                          const float* __restrict__ b1, const float* __restrict__ g2,
                          const float* __restrict__ be2, float* __restrict__ A,
                          float* __restrict__ Bc, float* __restrict__ Cc) {
  int co = threadIdx.x;
  float s = 0.f, s2 = 0.f;
  for (int k = 0; k < 8; ++k) { s += part[(co * 8 + k) * 2]; s2 += part[(co * 8 + k) * 2 + 1]; }
  const float inv = 1.f / 65536.f;
  float m = s * inv, var = s2 * inv - m * m;
  float rs = rsqrtf(var + EPS);
  float gg = rs * g2[co];
  A[co] = al1[co] * gg;
  Bc[co] = (b1[co] - m) * gg + be2[co];
  Cc[co] = gg;
}

// ---------------- binarize2 -> bf16 +-1, layout [b][px][256ci] (MFMA path) ----------------
__global__ __launch_bounds__(256) void k_bin2_bf16(const short* __restrict__ S1, const float* __restrict__ A,
                                                   const float* __restrict__ Bc, const float* __restrict__ Cc,
                                                   const float* __restrict__ temb, uint4* __restrict__ h2u4) {
  __shared__ uint4 tile[64 * 32]; // [px][32 x 16B], slot-swizzled
  int b = blockIdx.x >> 6;
  int px0 = (blockIdx.x & 63) << 6;
  int pxl = threadIdx.x & 63, quad = threadIdx.x >> 6;
  const short* sp = S1 + ((size_t)b << 20) + (px0 + pxl);
  const float* tp = temb + (b << 8);
  #pragma unroll 1
  for (int g = 0; g < 8; ++g) {
    uint d[4];
    #pragma unroll
    for (int h = 0; h < 4; ++h) {
      int c0 = quad * 64 + g * 8 + h * 2;
      float v0 = A[c0] * (float)sp[(size_t)c0 << 12] + Bc[c0] + Cc[c0] * tp[c0];
      float v1 = A[c0 + 1] * (float)sp[(size_t)(c0 + 1) << 12] + Bc[c0 + 1] + Cc[c0 + 1] * tp[c0 + 1];
      uint s0 = (v0 > 0.f) ? 0x3F80u : 0xBF80u;
      uint s1 = (v1 > 0.f) ? 0x3F80u : 0xBF80u;
      d[h] = s0 | (s1 << 16);
    }
    int slot = quad * 8 + g;
    tile[pxl * 32 + (slot ^ (pxl & 7))] = make_uint4(d[0], d[1], d[2], d[3]);
  }
  __syncthreads();
  uint4* dst = h2u4 + ((size_t)(b << 12) + px0) * 32;
  #pragma unroll
  for (int k = 0; k < 8; ++k) {
    int c = k * 256 + threadIdx.x;
    int px = c >> 5, slot = c & 31;
    dst[c] = tile[px * 32 + (slot ^ (px & 7))];
  }
}

// ---------------- conv2 MFMA v4: 2 rows/block + A-fragment register pipeline ----------------
// 512 blocks = (b, y-pair) XCD-swizzled; 4 waves; wave w: co = w*64..+63, px = 2 rows x 64.
// (tap,kc) steps fully unrolled; Av double-buffered (parity static) so step n+1's 4 coalesced
// A-loads issue before step n's 32 MFMAs -> L2 latency hidden under matrix work.
__global__ __launch_bounds__(256, 2) void k_conv2_mfma(const ushort* __restrict__ h2,
                                                       const ushort* __restrict__ wT,
                                                       const float* __restrict__ al2,
                                                       float* __restrict__ out) {
  __shared__ ushort act[4 * 66 * 128]; // 67584 B
  int bidx = blockIdx.x;
  int s = (bidx & 7) * 64 + (bidx >> 3); // bijective, XCD-contiguous over 512
  int b = s >> 5, y0 = (s & 31) << 1;
  int lane = threadIdx.x & 63, wave = threadIdx.x >> 6;
  int co0 = wave << 6;
  int l15 = lane & 15, lk = lane >> 4;

  f32x4 acc[4][8] = {};

  const uint4* h2g = (const uint4*)h2;
  uint4* a4 = (uint4*)act;
  // per-thread A-load base offset within a slice: (co0 + ct*16 + l15)*32 + lk*8
  const size_t abase = (size_t)((co0 + l15) << 5) + (lk << 3);

#define LOAD_AV(dst, chunkv, tpv, kcv)                                                        \
  {                                                                                           \
    const ushort* wtp_ = wT + ((size_t)((((tpv) << 3) + ((chunkv) << 2) + (kcv))) << 13);     \
    _Pragma("unroll")                                                                         \
    for (int ct_ = 0; ct_ < 4; ++ct_)                                                         \
      dst[ct_] = *(const bf16x8*)(wtp_ + abase + (ct_ << 9));                                 \
  }

  #pragma unroll 1
  for (int chunk = 0; chunk < 2; ++chunk) {
    if (chunk) __syncthreads();
    // stage 4 rows (y0-1..y0+2) x 66 x 128ci bf16 (zero halo): 4224 uint4, swizzled
    #pragma unroll 1
    for (int i = 0; i < 17; ++i) {
      int idx = i * 256 + threadIdx.x;
      if (idx < 4224) {
        int q = idx & 15, rowxz = idx >> 4;
        int xz = rowxz % 66, r = rowxz / 66;
        int yy = y0 + r - 1, xx = xz - 1;
        uint4 v = make_uint4(0, 0, 0, 0);
        if (((unsigned)yy < 64u) && ((unsigned)xx < 64u))
          v = h2g[(size_t)((b << 12) | (yy << 6) | xx) * 32 + chunk * 16 + q];
        a4[((rowxz << 4) + q) ^ (rowxz & 7)] = v;
      }
    }
    __syncthreads();

    bf16x8 Av2[2][4];
    LOAD_AV(Av2[0], chunk, 0, 0);

    #pragma unroll
    for (int tp = 0; tp < 9; ++tp) {
      int ty = tp / 3, tx = tp % 3;
      #pragma unroll
      for (int kc = 0; kc < 4; ++kc) {
        const int step = tp * 4 + kc;
        const int cur = step & 1, nxt = cur ^ 1;
        // prefetch next step's A fragments (coalesced 1KB loads)
        if (step < 35) {
          const int ntp = (kc < 3) ? tp : tp + 1;
          const int nkc = (kc < 3) ? kc + 1 : 0;
          LOAD_AV(Av2[nxt], chunk, ntp, nkc);
        }
        #pragma unroll
        for (int r = 0; r < 2; ++r) {
          bf16x8 Bv[4];
          #pragma unroll
          for (int pt = 0; pt < 4; ++pt) {
            int xi = (r + ty) * 66 + tx + pt * 16 + l15;
            int u = (((xi << 4) + (kc << 2) + lk) ^ (xi & 7));
            Bv[pt] = *(bf16x8*)&act[u << 3];
          }
          #pragma unroll
          for (int ct = 0; ct < 4; ++ct)
            #pragma unroll
            for (int pt = 0; pt < 4; ++pt)
              acc[ct][r * 4 + pt] = __builtin_amdgcn_mfma_f32_16x16x32_bf16(Av2[cur][ct], Bv[pt], acc[ct][r * 4 + pt], 0, 0, 0);
        }
      }
    }
  }
#undef LOAD_AV

  // epilogue: RMW out, 2 rows
  #pragma unroll
  for (int ct = 0; ct < 4; ++ct) {
    #pragma unroll
    for (int r = 0; r < 2; ++r) {
      #pragma unroll
      for (int pt = 0; pt < 4; ++pt) {
        int x = pt * 16 + l15;
        float* ob = out + ((size_t)b << 20) + ((y0 + r) << 6) + x;
        #pragma unroll
        for (int j = 0; j < 4; ++j) {
          int co = co0 + ct * 16 + lk * 4 + j;
          float* p = ob + ((size_t)co << 12);
          *p = fmaf(al2[co], acc[ct][r * 4 + pt][j], *p);
        }
      }
    }
  }
}

// ---------------- fallback path (R4-proven): packed bin2 + popcount conv2 ----------------
__global__ __launch_bounds__(256) void k_bin2_packed(const short* __restrict__ S1, const float* __restrict__ A,
                                                     const float* __restrict__ Bc, const float* __restrict__ Cc,
                                                     const float* __restrict__ temb, uint4* __restrict__ hbin) {
  int pg = blockIdx.x * 256 + threadIdx.x;
  int b = pg >> 12, p = pg & 4095;
  int c0 = blockIdx.y << 7;
  const short* sp = S1 + ((size_t)b << 20) + p;
  const float* tp = temb + (b << 8);
  uint w[4];
  #pragma unroll
  for (int wd = 0; wd < 4; ++wd) {
    uint acc = 0;
    #pragma unroll
    for (int i = 0; i < 32; ++i) {
      int co = c0 + wd * 32 + i;
      float v = A[co] * (float)sp[(size_t)co << 12] + Bc[co] + Cc[co] * tp[co];
      acc |= (v > 0.f ? 1u : 0u) << i;
    }
    w[wd] = acc;
  }
  hbin[pg * 2 + blockIdx.y] = make_uint4(w[0], w[1], w[2], w[3]);
}

__global__ __launch_bounds__(256, 1) void k_conv2_pop(const uint4* __restrict__ hbin, const uint* __restrict__ wb2,
                                                      const int* __restrict__ base2, const float* __restrict__ al2,
                                                      float* __restrict__ out) {
  __shared__ uint wlds[32 * 72];
  __shared__ int blds[9 * 32];
  int co0 = blockIdx.y << 5;
  #pragma unroll
  for (int k = 0; k < 9; ++k) wlds[k * 256 + threadIdx.x] = wb2[co0 * 72 + k * 256 + threadIdx.x];
  #pragma unroll
  for (int k = 0; k < 2; ++k) {
    int idx = k * 256 + threadIdx.x;
    if (idx < 288) blds[idx] = base2[(idx >> 5) * 256 + co0 + (idx & 31)];
  }
  int bt = blockIdx.x;
  int b = bt >> 4;
  int y = ((bt & 15) << 2) | (threadIdx.x >> 6);
  int cx = threadIdx.x & 63;
  uint nb[9][8];
  #pragma unroll
  for (int dy = -1; dy <= 1; ++dy)
    #pragma unroll
    for (int dx = -1; dx <= 1; ++dx) {
      int tp = (dy + 1) * 3 + (dx + 1);
      int yy = y + dy, xx = cx + dx;
      bool v = ((unsigned)yy < 64u) && ((unsigned)xx < 64u);
      uint4 q0 = make_uint4(0, 0, 0, 0), q1 = make_uint4(0, 0, 0, 0);
      if (v) {
        int pix = (b << 12) | (yy << 6) | xx;
        q0 = hbin[pix * 2 + 0];
        q1 = hbin[pix * 2 + 1];
      }
      nb[tp][0] = q0.x; nb[tp][1] = q0.y; nb[tp][2] = q0.z; nb[tp][3] = q0.w;
      nb[tp][4] = q1.x; nb[tp][5] = q1.y; nb[tp][6] = q1.z; nb[tp][7] = q1.w;
    }
  int pat = ((y == 0) ? 0 : ((y == 63) ? 6 : 3)) + ((cx == 0) ? 0 : ((cx == 63) ? 2 : 1));
  __syncthreads();

  int p = (y << 6) | cx;
  float* op = out + ((size_t)b << 20) + ((size_t)co0 << 12) + p;
  #pragma unroll 1
  for (int cc = 0; cc < 4; ++cc) {
    float ov[8];
    #pragma unroll
    for (int j = 0; j < 8; ++j) ov[j] = op[(size_t)(cc * 8 + j) << 12];
    #pragma unroll
    for (int j = 0; j < 8; ++j) {
      int co_l = cc * 8 + j;
      const uint4* wp4 = (const uint4*)(wlds + co_l * 72);
      uint m0 = 0, m1 = 0, m2 = 0, m3 = 0;
      #pragma unroll
      for (int tp = 0; tp < 9; ++tp) {
        uint4 wa = wp4[tp * 2 + 0];
        uint4 wb_ = wp4[tp * 2 + 1];
        m0 += __popc(nb[tp][0] ^ wa.x);
        m1 += __popc(nb[tp][1] ^ wa.y);
        m2 += __popc(nb[tp][2] ^ wa.z);
        m3 += __popc(nb[tp][3] ^ wa.w);
        m0 += __popc(nb[tp][4] ^ wb_.x);
        m1 += __popc(nb[tp][5] ^ wb_.y);
        m2 += __popc(nb[tp][6] ^ wb_.z);
        m3 += __popc(nb[tp][7] ^ wb_.w);
      }
      int acc = blds[pat * 32 + co_l] - 2 * (int)((m0 + m1) + (m2 + m3));
      ov[j] = fmaf(al2[co0 + co_l], (float)acc, ov[j]);
    }
    #pragma unroll
    for (int j = 0; j < 8; ++j) op[(size_t)(cc * 8 + j) << 12] = ov[j];
  }
}

extern "C" void kernel_launch(void* const* d_in, const int* in_sizes, int n_in,
                              void* d_out, int out_size, void* d_ws, size_t ws_size,
                              hipStream_t stream) {
  const float* x    = (const float*)d_in[0];
  const float* t    = (const float*)d_in[1];
  const float* bn1g = (const float*)d_in[2];
  const float* bn1b = (const float*)d_in[3];
  const float* w1   = (const float*)d_in[4];
  const float* b1   = (const float*)d_in[5];
  const float* tW   = (const float*)d_in[6];
  const float* tb   = (const float*)d_in[7];
  const float* bn2g = (const float*)d_in[8];
  const float* bn2b = (const float*)d_in[9];
  const float* w2   = (const float*)d_in[10];
  const float* b2   = (const float*)d_in[11];
  const float* wsk  = (const float*)d_in[12];
  const float* bsk  = (const float*)d_in[13];
  float* out = (float*)d_out;
  char* ws = (char*)d_ws;

  float* bn1part = (float*)(ws + 0);
  float* sc1     = (float*)(ws + 8192);
  float* sh1     = (float*)(ws + 8704);
  uint4* sbin    = (uint4*)(ws + 9216);      // 1 MB
  uint*  wb1     = (uint*) (ws + 1057792);
  float* al1     = (float*)(ws + 1094656);
  uint*  wb2     = (uint*) (ws + 1095680);
  float* al2     = (float*)(ws + 1169408);
  float* swkT    = (float*)(ws + 1170432);
  float* temb    = (float*)(ws + 1301504);
  float* bn2part = (float*)(ws + 1317888);
  float* A2      = (float*)(ws + 1334272);
  float* Bc2     = (float*)(ws + 1335296);
  float* Cc2     = (float*)(ws + 1336320);
  int*   base1g  = (int*)  (ws + 1337344);
  int*   base2g  = (int*)  (ws + 1346560);
  uint4* hbin    = (uint4*)(ws + 1355776);   // 2 MB (fallback only)
  ushort* wT2    = (ushort*)(ws + 3452928);  // 1.18 MB (transposed MFMA weights)
  short* S1      = (short*)(ws + 4632576);   // 33.5 MB
  ushort* h2     = (ushort*)(ws + 38187008); // 33.5 MB (MFMA path only)
  const size_t WS_NEED_MFMA = 71741440ULL;
  bool use_mfma = (ws_size >= WS_NEED_MFMA);

  k_bn1_part<<<dim3(128, 8), 256, 0, stream>>>(x, bn1part);
  k_bn1_fin<<<1, 128, 0, stream>>>(bn1part, bn1g, bn1b, sc1, sh1);
  k_packw1<<<256, 128, 0, stream>>>(w1, wb1, al1);
  k_packw2<<<256, 256, 0, stream>>>(w2, wb2, al2, wT2);
  k_base<<<1, 256, 0, stream>>>(wb1, wb2, base1g, base2g);
  k_packws<<<256, 128, 0, stream>>>(wsk, swkT);
  k_temb<<<16, 256, 0, stream>>>(t, tW, tb, temb);
  k_skip<<<dim3(1024, 4), 256, 0, stream>>>(x, swkT, bsk, b2, sc1, sh1, (uint*)sbin, out);
  k_conv1<<<dim3(256, 8), 256, 0, stream>>>(sbin, wb1, base1g, S1);
  k_bn2_part<<<dim3(256, 8), 256, 0, stream>>>(S1, al1, b1, temb, bn2part);
  k_bn2_fin<<<1, 256, 0, stream>>>(bn2part, al1, b1, bn2g, bn2b, A2, Bc2, Cc2);
  if (use_mfma) {
    k_bin2_bf16<<<1024, 256, 0, stream>>>(S1, A2, Bc2, Cc2, temb, (uint4*)h2);
    k_conv2_mfma<<<512, 256, 0, stream>>>(h2, wT2, al2, out);
  } else {
    k_bin2_packed<<<dim3(256, 2), 256, 0, stream>>>(S1, A2, Bc2, Cc2, temb, hbin);
    k_conv2_pop<<<dim3(256, 8), 256, 0, stream>>>(hbin, wb2, base2g, al2, out);
  }
}

// Round 11
// 240.160 us; speedup vs baseline: 1.9992x; 1.9992x over previous
//
#include <hip/hip_runtime.h>
#include <stdint.h>

typedef unsigned int uint;
typedef short bf16x8 __attribute__((ext_vector_type(8)));
typedef float f32x4 __attribute__((ext_vector_type(4)));

#define EPS 1e-5f

// Shapes: B=16, Cin=128, Cout=256, T=512, H=W=64, HW=4096, NPIX=65536

// ---------------- BN1 stats ----------------
__global__ __launch_bounds__(256) void k_bn1_part(const float* __restrict__ x, float* __restrict__ part) {
  int c = blockIdx.x, chunk = blockIdx.y;
  float s = 0.f, s2 = 0.f;
  #pragma unroll
  for (int jb = 0; jb < 2; ++jb) {
    int b = chunk * 2 + jb;
    const float4* xb = (const float4*)(x + (((size_t)((b << 7) | c)) << 12));
    #pragma unroll
    for (int k = 0; k < 4; ++k) {
      float4 q = xb[k * 256 + threadIdx.x];
      s += (q.x + q.y) + (q.z + q.w);
      s2 += q.x * q.x + q.y * q.y + q.z * q.z + q.w * q.w;
    }
  }
  #pragma unroll
  for (int off = 32; off > 0; off >>= 1) { s += __shfl_down(s, off); s2 += __shfl_down(s2, off); }
  __shared__ float ls[4], ls2[4];
  int wid = threadIdx.x >> 6, lane = threadIdx.x & 63;
  if (lane == 0) { ls[wid] = s; ls2[wid] = s2; }
  __syncthreads();
  if (threadIdx.x == 0) {
    part[(c * 8 + chunk) * 2 + 0] = ls[0] + ls[1] + ls[2] + ls[3];
    part[(c * 8 + chunk) * 2 + 1] = ls2[0] + ls2[1] + ls2[2] + ls2[3];
  }
}

__global__ void k_bn1_fin(const float* __restrict__ part, const float* __restrict__ g,
                          const float* __restrict__ be, float* __restrict__ sc, float* __restrict__ sh) {
  int c = threadIdx.x;
  float s = 0.f, s2 = 0.f;
  for (int k = 0; k < 8; ++k) { s += part[(c * 8 + k) * 2]; s2 += part[(c * 8 + k) * 2 + 1]; }
  const float inv = 1.f / 65536.f;
  float m = s * inv, var = s2 * inv - m * m;
  float rs = rsqrtf(var + EPS);
  float scale = rs * g[c];
  sc[c] = scale;
  sh[c] = be[c] - m * scale;
}

// ---------------- weight packing ----------------
__global__ __launch_bounds__(128) void k_packw1(const float* __restrict__ w1, uint* __restrict__ wb,
                                                float* __restrict__ alpha) {
  int co = blockIdx.x, wid = threadIdx.x >> 6, lane = threadIdx.x & 63;
  const float* wp = w1 + (co * 128 + threadIdx.x) * 9;
  float wv[9]; float s = 0.f;
  #pragma unroll
  for (int tp = 0; tp < 9; ++tp) { wv[tp] = wp[tp]; s += fabsf(wv[tp]); }
  #pragma unroll
  for (int tp = 0; tp < 9; ++tp) {
    unsigned long long m = __ballot(wv[tp] > 0.f);
    if (lane == 0) {
      wb[(co * 9 + tp) * 4 + wid * 2 + 0] = (uint)m;
      wb[(co * 9 + tp) * 4 + wid * 2 + 1] = (uint)(m >> 32);
    }
  }
  #pragma unroll
  for (int off = 32; off > 0; off >>= 1) s += __shfl_down(s, off);
  __shared__ float l2[2];
  if (lane == 0) l2[wid] = s;
  __syncthreads();
  if (threadIdx.x == 0) alpha[co] = (l2[0] + l2[1]) * (1.f / 1152.f);
}

// emits bf16 sign weights TRANSPOSED for MFMA: wT[slice=(tap*8+chunk*4+kc)][co][32ci_local]
__global__ __launch_bounds__(256) void k_packw2(const float* __restrict__ w2, uint* __restrict__ wb,
                                                float* __restrict__ alpha, ushort* __restrict__ wT) {
  int co = blockIdx.x, wid = threadIdx.x >> 6, lane = threadIdx.x & 63;
  int ci = threadIdx.x;
  const float* wp = w2 + (co * 256 + ci) * 9;
  float wv[9]; float s = 0.f;
  #pragma unroll
  for (int tp = 0; tp < 9; ++tp) { wv[tp] = wp[tp]; s += fabsf(wv[tp]); }
  int chunk = ci >> 7, kc = (ci >> 5) & 3, cil = ci & 31;
  #pragma unroll
  for (int tp = 0; tp < 9; ++tp) {
    wT[(((tp << 3) + (chunk << 2) + kc) << 13) + (co << 5) + cil] = (wv[tp] > 0.f) ? 0x3F80u : 0xBF80u;
    unsigned long long m = __ballot(wv[tp] > 0.f);
    if (lane == 0) {
      wb[(co * 9 + tp) * 8 + wid * 2 + 0] = (uint)m;
      wb[(co * 9 + tp) * 8 + wid * 2 + 1] = (uint)(m >> 32);
    }
  }
  #pragma unroll
  for (int off = 32; off > 0; off >>= 1) s += __shfl_down(s, off);
  __shared__ float l4[4];
  if (lane == 0) l4[wid] = s;
  __syncthreads();
  if (threadIdx.x == 0) alpha[co] = (l4[0] + l4[1] + l4[2] + l4[3]) * (1.f / 2304.f);
}

__global__ __launch_bounds__(256) void k_base(const uint* __restrict__ wb1, const uint* __restrict__ wb2,
                                              int* __restrict__ base1, int* __restrict__ base2) {
  int co = threadIdx.x;
  int pc1[9], pc2[9];
  #pragma unroll
  for (int tp = 0; tp < 9; ++tp) {
    uint a = 0;
    #pragma unroll
    for (int k = 0; k < 4; ++k) a += __popc(wb1[co * 36 + tp * 4 + k]);
    pc1[tp] = (int)a;
    uint b = 0;
    #pragma unroll
    for (int k = 0; k < 8; ++k) b += __popc(wb2[co * 72 + tp * 8 + k]);
    pc2[tp] = (int)b;
  }
  #pragma unroll
  for (int pat = 0; pat < 9; ++pat) {
    int yt = pat / 3, xt = pat % 3;
    int b1v = 1152, b2v = 2304;
    #pragma unroll
    for (int tp = 0; tp < 9; ++tp) {
      int dy = tp / 3 - 1, dx = tp % 3 - 1;
      bool inv = (dy < 0 && yt == 0) || (dy > 0 && yt == 2) || (dx < 0 && xt == 0) || (dx > 0 && xt == 2);
      if (inv) { b1v -= 128 - 2 * pc1[tp]; b2v -= 256 - 2 * pc2[tp]; }
    }
    base1[pat * 256 + co] = b1v;
    base2[pat * 256 + co] = b2v;
  }
}

__global__ __launch_bounds__(128) void k_packws(const float* __restrict__ wsk, float* __restrict__ swT) {
  int co = blockIdx.x, ci = threadIdx.x;
  float v = wsk[co * 128 + ci];
  float s = fabsf(v);
  #pragma unroll
  for (int off = 32; off > 0; off >>= 1) s += __shfl_down(s, off);
  __shared__ float l2[2]; __shared__ float tot;
  int wid = threadIdx.x >> 6, lane = threadIdx.x & 63;
  if (lane == 0) l2[wid] = s;
  __syncthreads();
  if (threadIdx.x == 0) tot = (l2[0] + l2[1]) * (1.f / 128.f);
  __syncthreads();
  float a = tot;
  swT[ci * 256 + co] = (v > 0.f) ? a : -a;
}

// ---------------- temb ----------------
__global__ __launch_bounds__(256) void k_temb(const float* __restrict__ t, const float* __restrict__ tW,
                                              const float* __restrict__ tbias, float* __restrict__ temb) {
  int b = blockIdx.x, co = threadIdx.x;
  const float* tr = t + b * 512;
  const float* wr = tW + co * 512;
  float a0 = 0, a1 = 0, a2 = 0, a3 = 0;
  #pragma unroll 8
  for (int k = 0; k < 512; k += 4) {
    a0 = fmaf(tr[k + 0], wr[k + 0], a0);
    a1 = fmaf(tr[k + 1], wr[k + 1], a1);
    a2 = fmaf(tr[k + 2], wr[k + 2], a2);
    a3 = fmaf(tr[k + 3], wr[k + 3], a3);
  }
  temb[b * 256 + co] = (a0 + a1) + (a2 + a3) + tbias[co];
}

// ---------------- skip GEMM + fused bin1 ----------------
__global__ __launch_bounds__(256, 2) void k_skip(const float* __restrict__ x, const float* __restrict__ swT,
                                                 const float* __restrict__ bsk, const float* __restrict__ b2,
                                                 const float* __restrict__ sc1, const float* __restrict__ sh1,
                                                 uint* __restrict__ sbinw, float* __restrict__ out) {
  __shared__ float xs[128 * 64];
  __shared__ float wsl[128 * 64];
  int g = blockIdx.x;
  int b = g >> 6;
  int px0 = (g & 63) << 6;
  int co0 = blockIdx.y << 6;
  int t = threadIdx.x;

  {
    const float* xb = x + ((size_t)(b << 7) << 12) + px0;
    float4* xs4 = (float4*)xs;
    #pragma unroll
    for (int k = 0; k < 8; ++k) {
      int idx = k * 256 + t;
      int ci = idx >> 4, f4 = idx & 15;
      xs4[idx] = *(const float4*)(xb + ((size_t)ci << 12) + (f4 << 2));
    }
  }
  {
    float4* ws4 = (float4*)wsl;
    #pragma unroll
    for (int k = 0; k < 8; ++k) {
      int idx = k * 256 + t;
      int ci = idx >> 4, f4 = idx & 15;
      ws4[idx] = *(const float4*)(swT + ci * 256 + co0 + (f4 << 2));
    }
  }
  __syncthreads();

  if (blockIdx.y == 0) {
    int px = t & 63, wd = t >> 6;
    int ci0 = wd << 5;
    uint acc = 0;
    #pragma unroll
    for (int i = 0; i < 32; ++i) {
      int ci = ci0 + i;
      float v = xs[ci * 64 + px];
      acc |= ((v * sc1[ci] + sh1[ci]) > 0.f ? 1u : 0u) << i;
    }
    sbinw[(((size_t)b << 12) | (px0 + px)) * 4 + wd] = acc;
  }

  int tx = t & 15, ty = t >> 4;
  const float4* xs4 = (const float4*)xs;
  const float4* ws4 = (const float4*)wsl;
  float4 acc0 = make_float4(0, 0, 0, 0), acc1 = acc0, acc2 = acc0, acc3 = acc0;
  #pragma unroll 4
  for (int ci = 0; ci < 128; ++ci) {
    float4 xv = xs4[ci * 16 + tx];
    float4 wv = ws4[ci * 16 + ty];
    acc0.x = fmaf(wv.x, xv.x, acc0.x); acc0.y = fmaf(wv.x, xv.y, acc0.y);
    acc0.z = fmaf(wv.x, xv.z, acc0.z); acc0.w = fmaf(wv.x, xv.w, acc0.w);
    acc1.x = fmaf(wv.y, xv.x, acc1.x); acc1.y = fmaf(wv.y, xv.y, acc1.y);
    acc1.z = fmaf(wv.y, xv.z, acc1.z); acc1.w = fmaf(wv.y, xv.w, acc1.w);
    acc2.x = fmaf(wv.z, xv.x, acc2.x); acc2.y = fmaf(wv.z, xv.y, acc2.y);
    acc2.z = fmaf(wv.z, xv.z, acc2.z); acc2.w = fmaf(wv.z, xv.w, acc2.w);
    acc3.x = fmaf(wv.w, xv.x, acc3.x); acc3.y = fmaf(wv.w, xv.y, acc3.y);
    acc3.z = fmaf(wv.w, xv.z, acc3.z); acc3.w = fmaf(wv.w, xv.w, acc3.w);
  }

  float* op = out + ((size_t)b << 20) + px0 + (tx << 2);
  int cob = co0 + (ty << 2);
  float4 r;
  r = acc0; { float bb = bsk[cob + 0] + b2[cob + 0]; r.x += bb; r.y += bb; r.z += bb; r.w += bb; }
  *(float4*)(op + (size_t)(cob + 0) * 4096) = r;
  r = acc1; { float bb = bsk[cob + 1] + b2[cob + 1]; r.x += bb; r.y += bb; r.z += bb; r.w += bb; }
  *(float4*)(op + (size_t)(cob + 1) * 4096) = r;
  r = acc2; { float bb = bsk[cob + 2] + b2[cob + 2]; r.x += bb; r.y += bb; r.z += bb; r.w += bb; }
  *(float4*)(op + (size_t)(cob + 2) * 4096) = r;
  r = acc3; { float bb = bsk[cob + 3] + b2[cob + 3]; r.x += bb; r.y += bb; r.z += bb; r.w += bb; }
  *(float4*)(op + (size_t)(cob + 3) * 4096) = r;
}

// ---------------- conv1 (popcount, R4-proven) ----------------
__global__ __launch_bounds__(256, 1) void k_conv1(const uint4* __restrict__ sbin, const uint* __restrict__ wb1,
                                                  const int* __restrict__ base1, short* __restrict__ S1) {
  __shared__ uint wlds[32 * 36];
  __shared__ int blds[9 * 32];
  int co0 = blockIdx.y << 5;
  #pragma unroll
  for (int k = 0; k < 4; ++k) wlds[k * 256 + threadIdx.x] = wb1[co0 * 36 + k * 256 + threadIdx.x];
  if (threadIdx.x < 128) wlds[1024 + threadIdx.x] = wb1[co0 * 36 + 1024 + threadIdx.x];
  #pragma unroll
  for (int k = 0; k < 2; ++k) {
    int idx = k * 256 + threadIdx.x;
    if (idx < 288) blds[idx] = base1[(idx >> 5) * 256 + co0 + (idx & 31)];
  }

  int bt = blockIdx.x;
  int b = bt >> 4;
  int y = ((bt & 15) << 2) | (threadIdx.x >> 6);
  int cx = threadIdx.x & 63;
  uint nb[9][4];
  #pragma unroll
  for (int dy = -1; dy <= 1; ++dy)
    #pragma unroll
    for (int dx = -1; dx <= 1; ++dx) {
      int tp = (dy + 1) * 3 + (dx + 1);
      int yy = y + dy, xx = cx + dx;
      bool v = ((unsigned)yy < 64u) && ((unsigned)xx < 64u);
      uint4 q = make_uint4(0, 0, 0, 0);
      if (v) q = sbin[(b << 12) | (yy << 6) | xx];
      nb[tp][0] = q.x; nb[tp][1] = q.y; nb[tp][2] = q.z; nb[tp][3] = q.w;
    }
  int pat = ((y == 0) ? 0 : ((y == 63) ? 6 : 3)) + ((cx == 0) ? 0 : ((cx == 63) ? 2 : 1));
  __syncthreads();

  int p = (y << 6) | cx;
  short* op = S1 + ((size_t)b << 20) + ((size_t)co0 << 12) + p;
  #pragma unroll 1
  for (int cc = 0; cc < 4; ++cc) {
    short accv[8];
    #pragma unroll
    for (int j = 0; j < 8; ++j) {
      int co_l = cc * 8 + j;
      const uint4* wp4 = (const uint4*)(wlds + co_l * 36);
      uint m0 = 0, m1 = 0, m2 = 0, m3 = 0;
      #pragma unroll
      for (int tp = 0; tp < 9; ++tp) {
        uint4 w4 = wp4[tp];
        m0 += __popc(nb[tp][0] ^ w4.x);
        m1 += __popc(nb[tp][1] ^ w4.y);
        m2 += __popc(nb[tp][2] ^ w4.z);
        m3 += __popc(nb[tp][3] ^ w4.w);
      }
      accv[j] = (short)(blds[pat * 32 + co_l] - 2 * (int)((m0 + m1) + (m2 + m3)));
    }
    #pragma unroll
    for (int j = 0; j < 8; ++j) op[(size_t)(cc * 8 + j) << 12] = accv[j];
  }
}

// ---------------- BN2 stats ----------------
__global__ __launch_bounds__(256) void k_bn2_part(const short* __restrict__ S1, const float* __restrict__ al1,
                                                  const float* __restrict__ b1, const float* __restrict__ temb,
                                                  float* __restrict__ part) {
  int co = blockIdx.x, chunk = blockIdx.y;
  float a = al1[co], bb = b1[co];
  float s = 0.f, s2 = 0.f;
  #pragma unroll
  for (int jb = 0; jb < 2; ++jb) {
    int b = chunk * 2 + jb;
    float tb_ = bb + temb[(b << 8) | co];
    const uint4* sp = (const uint4*)(S1 + ((size_t)b << 20) + ((size_t)co << 12));
    #pragma unroll
    for (int k = 0; k < 2; ++k) {
      uint4 q = sp[k * 256 + threadIdx.x];
      uint ws[4] = {q.x, q.y, q.z, q.w};
      #pragma unroll
      for (int w = 0; w < 4; ++w) {
        float f0 = fmaf(a, (float)((short)(ws[w] & 0xffffu)), tb_);
        float f1 = fmaf(a, (float)((short)(ws[w] >> 16)), tb_);
        s += f0 + f1;
        s2 += f0 * f0 + f1 * f1;
      }
    }
  }
  #pragma unroll
  for (int off = 32; off > 0; off >>= 1) { s += __shfl_down(s, off); s2 += __shfl_down(s2, off); }
  __shared__ float ls[4], ls2[4];
  int wid = threadIdx.x >> 6, lane = threadIdx.x & 63;
  if (lane == 0) { ls[wid] = s; ls2[wid] = s2; }
  __syncthreads();
  if (threadIdx.x == 0) {
    part[(co * 8 + chunk) * 2 + 0] = ls[0] + ls[1] + ls[2] + ls[3];
    part[(co * 8 + chunk) * 2 + 1] = ls2[0] + ls2[1] + ls2[2] + ls2[3];
  }
}

__global__ void k_bn2_fin(const float* __restrict__ part, const float* __restrict__ al1,
                          const float* __restrict__ b1, const float* __restrict__ g2,
                          const float* __restrict__ be2, float* __restrict__ A,
                          float* __restrict__ Bc, float* __restrict__ Cc) {
  int co = threadIdx.x;
  float s = 0.f, s2 = 0.f;
  for (int k = 0; k < 8; ++k) { s += part[(co * 8 + k) * 2]; s2 += part[(co * 8 + k) * 2 + 1]; }
  const float inv = 1.f / 65536.f;
  float m = s * inv, var = s2 * inv - m * m;
  float rs = rsqrtf(var + EPS);
  float gg = rs * g2[co];
  A[co] = al1[co] * gg;
  Bc[co] = (b1[co] - m) * gg + be2[co];
  Cc[co] = gg;
}

// ---------------- binarize2 -> bf16 +-1, layout [b][px][256ci] (MFMA path) ----------------
__global__ __launch_bounds__(256) void k_bin2_bf16(const short* __restrict__ S1, const float* __restrict__ A,
                                                   const float* __restrict__ Bc, const float* __restrict__ Cc,
                                                   const float* __restrict__ temb, uint4* __restrict__ h2u4) {
  __shared__ uint4 tile[64 * 32]; // [px][32 x 16B], slot-swizzled
  int b = blockIdx.x >> 6;
  int px0 = (blockIdx.x & 63) << 6;
  int pxl = threadIdx.x & 63, quad = threadIdx.x >> 6;
  const short* sp = S1 + ((size_t)b << 20) + (px0 + pxl);
  const float* tp = temb + (b << 8);
  #pragma unroll 1
  for (int g = 0; g < 8; ++g) {
    uint d[4];
    #pragma unroll
    for (int h = 0; h < 4; ++h) {
      int c0 = quad * 64 + g * 8 + h * 2;
      float v0 = A[c0] * (float)sp[(size_t)c0 << 12] + Bc[c0] + Cc[c0] * tp[c0];
      float v1 = A[c0 + 1] * (float)sp[(size_t)(c0 + 1) << 12] + Bc[c0 + 1] + Cc[c0 + 1] * tp[c0 + 1];
      uint s0 = (v0 > 0.f) ? 0x3F80u : 0xBF80u;
      uint s1 = (v1 > 0.f) ? 0x3F80u : 0xBF80u;
      d[h] = s0 | (s1 << 16);
    }
    int slot = quad * 8 + g;
    tile[pxl * 32 + (slot ^ (pxl & 7))] = make_uint4(d[0], d[1], d[2], d[3]);
  }
  __syncthreads();
  uint4* dst = h2u4 + ((size_t)(b << 12) + px0) * 32;
  #pragma unroll
  for (int k = 0; k < 8; ++k) {
    int c = k * 256 + threadIdx.x;
    int px = c >> 5, slot = c & 31;
    dst[c] = tile[px * 32 + (slot ^ (px & 7))];
  }
}

// ---------------- conv2 MFMA v5: R8 structure + kc-level 2-deep Av pipeline (named buffers) ----------------
// 512 blocks = (b, y-pair) XCD-swizzled; 4 waves; wave w: co = w*64..+63, px = 2 rows x 64.
// Tap loop stays unroll-1 (R8's proven codegen scale). Within a tap, AvA/AvB alternate:
// each 4x1KB coalesced A-load issues before a 64-MFMA block that hides its L2 latency.
__global__ __launch_bounds__(256, 2) void k_conv2_mfma(const ushort* __restrict__ h2,
                                                       const ushort* __restrict__ wT,
                                                       const float* __restrict__ al2,
                                                       float* __restrict__ out) {
  __shared__ ushort act[4 * 66 * 128]; // 67584 B
  int bidx = blockIdx.x;
  int s = (bidx & 7) * 64 + (bidx >> 3); // bijective, XCD-contiguous over 512
  int b = s >> 5, y0 = (s & 31) << 1;
  int lane = threadIdx.x & 63, wave = threadIdx.x >> 6;
  int co0 = wave << 6;
  int l15 = lane & 15, lk = lane >> 4;

  f32x4 acc[4][8] = {};

  const uint4* h2g = (const uint4*)h2;
  uint4* a4 = (uint4*)act;
  const size_t abase = (size_t)((co0 + l15) << 5) + (lk << 3);

#define LOADAV(dst, ptr)                                                     \
  {                                                                          \
    _Pragma("unroll")                                                        \
    for (int ct_ = 0; ct_ < 4; ++ct_)                                        \
      dst[ct_] = *(const bf16x8*)((ptr) + abase + (ct_ << 9));               \
  }

#define KC_BLOCK(AV, kcv)                                                    \
  {                                                                          \
    _Pragma("unroll")                                                        \
    for (int r_ = 0; r_ < 2; ++r_) {                                         \
      bf16x8 Bv[4];                                                          \
      _Pragma("unroll")                                                      \
      for (int pt_ = 0; pt_ < 4; ++pt_) {                                    \
        int xi_ = (r_ + ty) * 66 + tx + pt_ * 16 + l15;                      \
        int u_ = (((xi_ << 4) + ((kcv) << 2) + lk) ^ (xi_ & 7));             \
        Bv[pt_] = *(bf16x8*)&act[u_ << 3];                                   \
      }                                                                      \
      _Pragma("unroll")                                                      \
      for (int ct_ = 0; ct_ < 4; ++ct_)                                      \
        _Pragma("unroll")                                                    \
        for (int pt_ = 0; pt_ < 4; ++pt_)                                    \
          acc[ct_][r_ * 4 + pt_] = __builtin_amdgcn_mfma_f32_16x16x32_bf16(  \
              AV[ct_], Bv[pt_], acc[ct_][r_ * 4 + pt_], 0, 0, 0);            \
    }                                                                        \
  }

  #pragma unroll 1
  for (int chunk = 0; chunk < 2; ++chunk) {
    if (chunk) __syncthreads();
    // stage 4 rows (y0-1..y0+2) x 66 x 128ci bf16 (zero halo): 4224 uint4, swizzled
    #pragma unroll 1
    for (int i = 0; i < 17; ++i) {
      int idx = i * 256 + threadIdx.x;
      if (idx < 4224) {
        int q = idx & 15, rowxz = idx >> 4;
        int xz = rowxz % 66, r = rowxz / 66;
        int yy = y0 + r - 1, xx = xz - 1;
        uint4 v = make_uint4(0, 0, 0, 0);
        if (((unsigned)yy < 64u) && ((unsigned)xx < 64u))
          v = h2g[(size_t)((b << 12) | (yy << 6) | xx) * 32 + chunk * 16 + q];
        a4[((rowxz << 4) + q) ^ (rowxz & 7)] = v;
      }
    }
    __syncthreads();

    const ushort* wch = wT + ((size_t)chunk << 15); // chunk*4 slices * 8192
    bf16x8 AvA[4], AvB[4];
    LOADAV(AvA, wch); // tap0, kc0

    #pragma unroll 1
    for (int tp = 0; tp < 9; ++tp) {
      int ty = tp / 3, tx = tp % 3;
      const ushort* wtp = wch + ((size_t)tp << 16);              // tp*8 slices
      const ushort* wnx = (tp < 8) ? (wtp + (1 << 16)) : wtp;    // next tap's kc0 (clamped)

      LOADAV(AvB, wtp + (1 << 13));  KC_BLOCK(AvA, 0);
      LOADAV(AvA, wtp + (2 << 13));  KC_BLOCK(AvB, 1);
      LOADAV(AvB, wtp + (3 << 13));  KC_BLOCK(AvA, 2);
      LOADAV(AvA, wnx);              KC_BLOCK(AvB, 3);
    }
  }
#undef LOADAV
#undef KC_BLOCK

  // epilogue: RMW out, 2 rows
  #pragma unroll
  for (int ct = 0; ct < 4; ++ct) {
    #pragma unroll
    for (int r = 0; r < 2; ++r) {
      #pragma unroll
      for (int pt = 0; pt < 4; ++pt) {
        int x = pt * 16 + l15;
        float* ob = out + ((size_t)b << 20) + ((y0 + r) << 6) + x;
        #pragma unroll
        for (int j = 0; j < 4; ++j) {
          int co = co0 + ct * 16 + lk * 4 + j;
          float* p = ob + ((size_t)co << 12);
          *p = fmaf(al2[co], acc[ct][r * 4 + pt][j], *p);
        }
      }
    }
  }
}

// ---------------- fallback path (R4-proven): packed bin2 + popcount conv2 ----------------
__global__ __launch_bounds__(256) void k_bin2_packed(const short* __restrict__ S1, const float* __restrict__ A,
                                                     const float* __restrict__ Bc, const float* __restrict__ Cc,
                                                     const float* __restrict__ temb, uint4* __restrict__ hbin) {
  int pg = blockIdx.x * 256 + threadIdx.x;
  int b = pg >> 12, p = pg & 4095;
  int c0 = blockIdx.y << 7;
  const short* sp = S1 + ((size_t)b << 20) + p;
  const float* tp = temb + (b << 8);
  uint w[4];
  #pragma unroll
  for (int wd = 0; wd < 4; ++wd) {
    uint acc = 0;
    #pragma unroll
    for (int i = 0; i < 32; ++i) {
      int co = c0 + wd * 32 + i;
      float v = A[co] * (float)sp[(size_t)co << 12] + Bc[co] + Cc[co] * tp[co];
      acc |= (v > 0.f ? 1u : 0u) << i;
    }
    w[wd] = acc;
  }
  hbin[pg * 2 + blockIdx.y] = make_uint4(w[0], w[1], w[2], w[3]);
}

__global__ __launch_bounds__(256, 1) void k_conv2_pop(const uint4* __restrict__ hbin, const uint* __restrict__ wb2,
                                                      const int* __restrict__ base2, const float* __restrict__ al2,
                                                      float* __restrict__ out) {
  __shared__ uint wlds[32 * 72];
  __shared__ int blds[9 * 32];
  int co0 = blockIdx.y << 5;
  #pragma unroll
  for (int k = 0; k < 9; ++k) wlds[k * 256 + threadIdx.x] = wb2[co0 * 72 + k * 256 + threadIdx.x];
  #pragma unroll
  for (int k = 0; k < 2; ++k) {
    int idx = k * 256 + threadIdx.x;
    if (idx < 288) blds[idx] = base2[(idx >> 5) * 256 + co0 + (idx & 31)];
  }
  int bt = blockIdx.x;
  int b = bt >> 4;
  int y = ((bt & 15) << 2) | (threadIdx.x >> 6);
  int cx = threadIdx.x & 63;
  uint nb[9][8];
  #pragma unroll
  for (int dy = -1; dy <= 1; ++dy)
    #pragma unroll
    for (int dx = -1; dx <= 1; ++dx) {
      int tp = (dy + 1) * 3 + (dx + 1);
      int yy = y + dy, xx = cx + dx;
      bool v = ((unsigned)yy < 64u) && ((unsigned)xx < 64u);
      uint4 q0 = make_uint4(0, 0, 0, 0), q1 = make_uint4(0, 0, 0, 0);
      if (v) {
        int pix = (b << 12) | (yy << 6) | xx;
        q0 = hbin[pix * 2 + 0];
        q1 = hbin[pix * 2 + 1];
      }
      nb[tp][0] = q0.x; nb[tp][1] = q0.y; nb[tp][2] = q0.z; nb[tp][3] = q0.w;
      nb[tp][4] = q1.x; nb[tp][5] = q1.y; nb[tp][6] = q1.z; nb[tp][7] = q1.w;
    }
  int pat = ((y == 0) ? 0 : ((y == 63) ? 6 : 3)) + ((cx == 0) ? 0 : ((cx == 63) ? 2 : 1));
  __syncthreads();

  int p = (y << 6) | cx;
  float* op = out + ((size_t)b << 20) + ((size_t)co0 << 12) + p;
  #pragma unroll 1
  for (int cc = 0; cc < 4; ++cc) {
    float ov[8];
    #pragma unroll
    for (int j = 0; j < 8; ++j) ov[j] = op[(size_t)(cc * 8 + j) << 12];
    #pragma unroll
    for (int j = 0; j < 8; ++j) {
      int co_l = cc * 8 + j;
      const uint4* wp4 = (const uint4*)(wlds + co_l * 72);
      uint m0 = 0, m1 = 0, m2 = 0, m3 = 0;
      #pragma unroll
      for (int tp = 0; tp < 9; ++tp) {
        uint4 wa = wp4[tp * 2 + 0];
        uint4 wb_ = wp4[tp * 2 + 1];
        m0 += __popc(nb[tp][0] ^ wa.x);
        m1 += __popc(nb[tp][1] ^ wa.y);
        m2 += __popc(nb[tp][2] ^ wa.z);
        m3 += __popc(nb[tp][3] ^ wa.w);
        m0 += __popc(nb[tp][4] ^ wb_.x);
        m1 += __popc(nb[tp][5] ^ wb_.y);
        m2 += __popc(nb[tp][6] ^ wb_.z);
        m3 += __popc(nb[tp][7] ^ wb_.w);
      }
      int acc = blds[pat * 32 + co_l] - 2 * (int)((m0 + m1) + (m2 + m3));
      ov[j] = fmaf(al2[co0 + co_l], (float)acc, ov[j]);
    }
    #pragma unroll
    for (int j = 0; j < 8; ++j) op[(size_t)(cc * 8 + j) << 12] = ov[j];
  }
}

extern "C" void kernel_launch(void* const* d_in, const int* in_sizes, int n_in,
                              void* d_out, int out_size, void* d_ws, size_t ws_size,
                              hipStream_t stream) {
  const float* x    = (const float*)d_in[0];
  const float* t    = (const float*)d_in[1];
  const float* bn1g = (const float*)d_in[2];
  const float* bn1b = (const float*)d_in[3];
  const float* w1   = (const float*)d_in[4];
  const float* b1   = (const float*)d_in[5];
  const float* tW   = (const float*)d_in[6];
  const float* tb   = (const float*)d_in[7];
  const float* bn2g = (const float*)d_in[8];
  const float* bn2b = (const float*)d_in[9];
  const float* w2   = (const float*)d_in[10];
  const float* b2   = (const float*)d_in[11];
  const float* wsk  = (const float*)d_in[12];
  const float* bsk  = (const float*)d_in[13];
  float* out = (float*)d_out;
  char* ws = (char*)d_ws;

  float* bn1part = (float*)(ws + 0);
  float* sc1     = (float*)(ws + 8192);
  float* sh1     = (float*)(ws + 8704);
  uint4* sbin    = (uint4*)(ws + 9216);      // 1 MB
  uint*  wb1     = (uint*) (ws + 1057792);
  float* al1     = (float*)(ws + 1094656);
  uint*  wb2     = (uint*) (ws + 1095680);
  float* al2     = (float*)(ws + 1169408);
  float* swkT    = (float*)(ws + 1170432);
  float* temb    = (float*)(ws + 1301504);
  float* bn2part = (float*)(ws + 1317888);
  float* A2      = (float*)(ws + 1334272);
  float* Bc2     = (float*)(ws + 1335296);
  float* Cc2     = (float*)(ws + 1336320);
  int*   base1g  = (int*)  (ws + 1337344);
  int*   base2g  = (int*)  (ws + 1346560);
  uint4* hbin    = (uint4*)(ws + 1355776);   // 2 MB (fallback only)
  ushort* wT2    = (ushort*)(ws + 3452928);  // 1.18 MB (transposed MFMA weights)
  short* S1      = (short*)(ws + 4632576);   // 33.5 MB
  ushort* h2     = (ushort*)(ws + 38187008); // 33.5 MB (MFMA path only)
  const size_t WS_NEED_MFMA = 71741440ULL;
  bool use_mfma = (ws_size >= WS_NEED_MFMA);

  k_bn1_part<<<dim3(128, 8), 256, 0, stream>>>(x, bn1part);
  k_bn1_fin<<<1, 128, 0, stream>>>(bn1part, bn1g, bn1b, sc1, sh1);
  k_packw1<<<256, 128, 0, stream>>>(w1, wb1, al1);
  k_packw2<<<256, 256, 0, stream>>>(w2, wb2, al2, wT2);
  k_base<<<1, 256, 0, stream>>>(wb1, wb2, base1g, base2g);
  k_packws<<<256, 128, 0, stream>>>(wsk, swkT);
  k_temb<<<16, 256, 0, stream>>>(t, tW, tb, temb);
  k_skip<<<dim3(1024, 4), 256, 0, stream>>>(x, swkT, bsk, b2, sc1, sh1, (uint*)sbin, out);
  k_conv1<<<dim3(256, 8), 256, 0, stream>>>(sbin, wb1, base1g, S1);
  k_bn2_part<<<dim3(256, 8), 256, 0, stream>>>(S1, al1, b1, temb, bn2part);
  k_bn2_fin<<<1, 256, 0, stream>>>(bn2part, al1, b1, bn2g, bn2b, A2, Bc2, Cc2);
  if (use_mfma) {
    k_bin2_bf16<<<1024, 256, 0, stream>>>(S1, A2, Bc2, Cc2, temb, (uint4*)h2);
    k_conv2_mfma<<<512, 256, 0, stream>>>(h2, wT2, al2, out);
  } else {
    k_bin2_packed<<<dim3(256, 2), 256, 0, stream>>>(S1, A2, Bc2, Cc2, temb, hbin);
    k_conv2_pop<<<dim3(256, 8), 256, 0, stream>>>(hbin, wb2, base2g, al2, out);
  }
}

// Round 12
// 231.696 us; speedup vs baseline: 2.0722x; 1.0365x over previous
//
#include <hip/hip_runtime.h>
#include <stdint.h>

typedef unsigned int uint;
typedef short bf16x8 __attribute__((ext_vector_type(8)));
typedef float f32x4 __attribute__((ext_vector_type(4)));

#define EPS 1e-5f

// Shapes: B=16, Cin=128, Cout=256, T=512, H=W=64, HW=4096, NPIX=65536

// ---------------- BN1 stats ----------------
__global__ __launch_bounds__(256) void k_bn1_part(const float* __restrict__ x, float* __restrict__ part) {
  int c = blockIdx.x, chunk = blockIdx.y;
  float s = 0.f, s2 = 0.f;
  #pragma unroll
  for (int jb = 0; jb < 2; ++jb) {
    int b = chunk * 2 + jb;
    const float4* xb = (const float4*)(x + (((size_t)((b << 7) | c)) << 12));
    #pragma unroll
    for (int k = 0; k < 4; ++k) {
      float4 q = xb[k * 256 + threadIdx.x];
      s += (q.x + q.y) + (q.z + q.w);
      s2 += q.x * q.x + q.y * q.y + q.z * q.z + q.w * q.w;
    }
  }
  #pragma unroll
  for (int off = 32; off > 0; off >>= 1) { s += __shfl_down(s, off); s2 += __shfl_down(s2, off); }
  __shared__ float ls[4], ls2[4];
  int wid = threadIdx.x >> 6, lane = threadIdx.x & 63;
  if (lane == 0) { ls[wid] = s; ls2[wid] = s2; }
  __syncthreads();
  if (threadIdx.x == 0) {
    part[(c * 8 + chunk) * 2 + 0] = ls[0] + ls[1] + ls[2] + ls[3];
    part[(c * 8 + chunk) * 2 + 1] = ls2[0] + ls2[1] + ls2[2] + ls2[3];
  }
}

__global__ void k_bn1_fin(const float* __restrict__ part, const float* __restrict__ g,
                          const float* __restrict__ be, float* __restrict__ sc, float* __restrict__ sh) {
  int c = threadIdx.x;
  float s = 0.f, s2 = 0.f;
  for (int k = 0; k < 8; ++k) { s += part[(c * 8 + k) * 2]; s2 += part[(c * 8 + k) * 2 + 1]; }
  const float inv = 1.f / 65536.f;
  float m = s * inv, var = s2 * inv - m * m;
  float rs = rsqrtf(var + EPS);
  float scale = rs * g[c];
  sc[c] = scale;
  sh[c] = be[c] - m * scale;
}

// ---------------- weight packing ----------------
// also emits bf16 sign weights transposed: wT1[slice=(tp*4+kc)][co][32ci]
__global__ __launch_bounds__(128) void k_packw1(const float* __restrict__ w1, uint* __restrict__ wb,
                                                float* __restrict__ alpha, ushort* __restrict__ wT1) {
  int co = blockIdx.x, wid = threadIdx.x >> 6, lane = threadIdx.x & 63;
  int ci = threadIdx.x;
  const float* wp = w1 + (co * 128 + ci) * 9;
  float wv[9]; float s = 0.f;
  #pragma unroll
  for (int tp = 0; tp < 9; ++tp) { wv[tp] = wp[tp]; s += fabsf(wv[tp]); }
  #pragma unroll
  for (int tp = 0; tp < 9; ++tp) {
    wT1[(((tp << 2) + (ci >> 5)) << 13) + (co << 5) + (ci & 31)] = (wv[tp] > 0.f) ? 0x3F80u : 0xBF80u;
    unsigned long long m = __ballot(wv[tp] > 0.f);
    if (lane == 0) {
      wb[(co * 9 + tp) * 4 + wid * 2 + 0] = (uint)m;
      wb[(co * 9 + tp) * 4 + wid * 2 + 1] = (uint)(m >> 32);
    }
  }
  #pragma unroll
  for (int off = 32; off > 0; off >>= 1) s += __shfl_down(s, off);
  __shared__ float l2[2];
  if (lane == 0) l2[wid] = s;
  __syncthreads();
  if (threadIdx.x == 0) alpha[co] = (l2[0] + l2[1]) * (1.f / 1152.f);
}

// emits bf16 sign weights TRANSPOSED for MFMA: wT[slice=(tap*8+chunk*4+kc)][co][32ci_local]
__global__ __launch_bounds__(256) void k_packw2(const float* __restrict__ w2, uint* __restrict__ wb,
                                                float* __restrict__ alpha, ushort* __restrict__ wT) {
  int co = blockIdx.x, wid = threadIdx.x >> 6, lane = threadIdx.x & 63;
  int ci = threadIdx.x;
  const float* wp = w2 + (co * 256 + ci) * 9;
  float wv[9]; float s = 0.f;
  #pragma unroll
  for (int tp = 0; tp < 9; ++tp) { wv[tp] = wp[tp]; s += fabsf(wv[tp]); }
  int chunk = ci >> 7, kc = (ci >> 5) & 3, cil = ci & 31;
  #pragma unroll
  for (int tp = 0; tp < 9; ++tp) {
    wT[(((tp << 3) + (chunk << 2) + kc) << 13) + (co << 5) + cil] = (wv[tp] > 0.f) ? 0x3F80u : 0xBF80u;
    unsigned long long m = __ballot(wv[tp] > 0.f);
    if (lane == 0) {
      wb[(co * 9 + tp) * 8 + wid * 2 + 0] = (uint)m;
      wb[(co * 9 + tp) * 8 + wid * 2 + 1] = (uint)(m >> 32);
    }
  }
  #pragma unroll
  for (int off = 32; off > 0; off >>= 1) s += __shfl_down(s, off);
  __shared__ float l4[4];
  if (lane == 0) l4[wid] = s;
  __syncthreads();
  if (threadIdx.x == 0) alpha[co] = (l4[0] + l4[1] + l4[2] + l4[3]) * (1.f / 2304.f);
}

__global__ __launch_bounds__(256) void k_base(const uint* __restrict__ wb1, const uint* __restrict__ wb2,
                                              int* __restrict__ base1, int* __restrict__ base2) {
  int co = threadIdx.x;
  int pc1[9], pc2[9];
  #pragma unroll
  for (int tp = 0; tp < 9; ++tp) {
    uint a = 0;
    #pragma unroll
    for (int k = 0; k < 4; ++k) a += __popc(wb1[co * 36 + tp * 4 + k]);
    pc1[tp] = (int)a;
    uint b = 0;
    #pragma unroll
    for (int k = 0; k < 8; ++k) b += __popc(wb2[co * 72 + tp * 8 + k]);
    pc2[tp] = (int)b;
  }
  #pragma unroll
  for (int pat = 0; pat < 9; ++pat) {
    int yt = pat / 3, xt = pat % 3;
    int b1v = 1152, b2v = 2304;
    #pragma unroll
    for (int tp = 0; tp < 9; ++tp) {
      int dy = tp / 3 - 1, dx = tp % 3 - 1;
      bool inv = (dy < 0 && yt == 0) || (dy > 0 && yt == 2) || (dx < 0 && xt == 0) || (dx > 0 && xt == 2);
      if (inv) { b1v -= 128 - 2 * pc1[tp]; b2v -= 256 - 2 * pc2[tp]; }
    }
    base1[pat * 256 + co] = b1v;
    base2[pat * 256 + co] = b2v;
  }
}

__global__ __launch_bounds__(128) void k_packws(const float* __restrict__ wsk, float* __restrict__ swT) {
  int co = blockIdx.x, ci = threadIdx.x;
  float v = wsk[co * 128 + ci];
  float s = fabsf(v);
  #pragma unroll
  for (int off = 32; off > 0; off >>= 1) s += __shfl_down(s, off);
  __shared__ float l2[2]; __shared__ float tot;
  int wid = threadIdx.x >> 6, lane = threadIdx.x & 63;
  if (lane == 0) l2[wid] = s;
  __syncthreads();
  if (threadIdx.x == 0) tot = (l2[0] + l2[1]) * (1.f / 128.f);
  __syncthreads();
  float a = tot;
  swT[ci * 256 + co] = (v > 0.f) ? a : -a;
}

// ---------------- temb ----------------
__global__ __launch_bounds__(256) void k_temb(const float* __restrict__ t, const float* __restrict__ tW,
                                              const float* __restrict__ tbias, float* __restrict__ temb) {
  int b = blockIdx.x, co = threadIdx.x;
  const float* tr = t + b * 512;
  const float* wr = tW + co * 512;
  float a0 = 0, a1 = 0, a2 = 0, a3 = 0;
  #pragma unroll 8
  for (int k = 0; k < 512; k += 4) {
    a0 = fmaf(tr[k + 0], wr[k + 0], a0);
    a1 = fmaf(tr[k + 1], wr[k + 1], a1);
    a2 = fmaf(tr[k + 2], wr[k + 2], a2);
    a3 = fmaf(tr[k + 3], wr[k + 3], a3);
  }
  temb[b * 256 + co] = (a0 + a1) + (a2 + a3) + tbias[co];
}

// ---------------- skip GEMM + fused bin1 (bf16 h1 when mfma1, bitpacked otherwise) ----------------
__global__ __launch_bounds__(256, 2) void k_skip(const float* __restrict__ x, const float* __restrict__ swT,
                                                 const float* __restrict__ bsk, const float* __restrict__ b2,
                                                 const float* __restrict__ sc1, const float* __restrict__ sh1,
                                                 uint* __restrict__ sbinw, ushort* __restrict__ h1w,
                                                 int mfma1, float* __restrict__ out) {
  __shared__ float xs[128 * 64];
  __shared__ float wsl[128 * 64];
  int g = blockIdx.x;
  int b = g >> 6;
  int px0 = (g & 63) << 6;
  int co0 = blockIdx.y << 6;
  int t = threadIdx.x;

  {
    const float* xb = x + ((size_t)(b << 7) << 12) + px0;
    float4* xs4 = (float4*)xs;
    #pragma unroll
    for (int k = 0; k < 8; ++k) {
      int idx = k * 256 + t;
      int ci = idx >> 4, f4 = idx & 15;
      xs4[idx] = *(const float4*)(xb + ((size_t)ci << 12) + (f4 << 2));
    }
  }
  {
    float4* ws4 = (float4*)wsl;
    #pragma unroll
    for (int k = 0; k < 8; ++k) {
      int idx = k * 256 + t;
      int ci = idx >> 4, f4 = idx & 15;
      ws4[idx] = *(const float4*)(swT + ci * 256 + co0 + (f4 << 2));
    }
  }
  __syncthreads();

  if (blockIdx.y == 0) {
    int px = t & 63, wd = t >> 6;
    int ci0 = wd << 5;
    if (mfma1) {
      ushort hv[32];
      #pragma unroll
      for (int i = 0; i < 32; ++i) {
        int ci = ci0 + i;
        float v = xs[ci * 64 + px];
        hv[i] = ((v * sc1[ci] + sh1[ci]) > 0.f) ? (ushort)0x3F80u : (ushort)0xBF80u;
      }
      uint4* dst = (uint4*)(h1w + (((size_t)((b << 12) | (px0 + px))) << 7) + (wd << 5));
      const uint4* src = (const uint4*)hv;
      dst[0] = src[0]; dst[1] = src[1]; dst[2] = src[2]; dst[3] = src[3];
    } else {
      uint acc = 0;
      #pragma unroll
      for (int i = 0; i < 32; ++i) {
        int ci = ci0 + i;
        float v = xs[ci * 64 + px];
        acc |= ((v * sc1[ci] + sh1[ci]) > 0.f ? 1u : 0u) << i;
      }
      sbinw[(((size_t)b << 12) | (px0 + px)) * 4 + wd] = acc;
    }
  }

  int tx = t & 15, ty = t >> 4;
  const float4* xs4 = (const float4*)xs;
  const float4* ws4 = (const float4*)wsl;
  float4 acc0 = make_float4(0, 0, 0, 0), acc1 = acc0, acc2 = acc0, acc3 = acc0;
  #pragma unroll 4
  for (int ci = 0; ci < 128; ++ci) {
    float4 xv = xs4[ci * 16 + tx];
    float4 wv = ws4[ci * 16 + ty];
    acc0.x = fmaf(wv.x, xv.x, acc0.x); acc0.y = fmaf(wv.x, xv.y, acc0.y);
    acc0.z = fmaf(wv.x, xv.z, acc0.z); acc0.w = fmaf(wv.x, xv.w, acc0.w);
    acc1.x = fmaf(wv.y, xv.x, acc1.x); acc1.y = fmaf(wv.y, xv.y, acc1.y);
    acc1.z = fmaf(wv.y, xv.z, acc1.z); acc1.w = fmaf(wv.y, xv.w, acc1.w);
    acc2.x = fmaf(wv.z, xv.x, acc2.x); acc2.y = fmaf(wv.z, xv.y, acc2.y);
    acc2.z = fmaf(wv.z, xv.z, acc2.z); acc2.w = fmaf(wv.z, xv.w, acc2.w);
    acc3.x = fmaf(wv.w, xv.x, acc3.x); acc3.y = fmaf(wv.w, xv.y, acc3.y);
    acc3.z = fmaf(wv.w, xv.z, acc3.z); acc3.w = fmaf(wv.w, xv.w, acc3.w);
  }

  float* op = out + ((size_t)b << 20) + px0 + (tx << 2);
  int cob = co0 + (ty << 2);
  float4 r;
  r = acc0; { float bb = bsk[cob + 0] + b2[cob + 0]; r.x += bb; r.y += bb; r.z += bb; r.w += bb; }
  *(float4*)(op + (size_t)(cob + 0) * 4096) = r;
  r = acc1; { float bb = bsk[cob + 1] + b2[cob + 1]; r.x += bb; r.y += bb; r.z += bb; r.w += bb; }
  *(float4*)(op + (size_t)(cob + 1) * 4096) = r;
  r = acc2; { float bb = bsk[cob + 2] + b2[cob + 2]; r.x += bb; r.y += bb; r.z += bb; r.w += bb; }
  *(float4*)(op + (size_t)(cob + 2) * 4096) = r;
  r = acc3; { float bb = bsk[cob + 3] + b2[cob + 3]; r.x += bb; r.y += bb; r.z += bb; r.w += bb; }
  *(float4*)(op + (size_t)(cob + 3) * 4096) = r;
}

// ---------------- conv1 MFMA: S1 = Wsgn1 conv h1, + fused BN2 partial sums ----------------
// 512 blocks = (b, y-pair) XCD-swizzled; 4 waves; K=1152 (9 taps x 4 kc of 32ci).
__global__ __launch_bounds__(256, 2) void k_conv1_mfma(const ushort* __restrict__ h1,
                                                       const ushort* __restrict__ wT1,
                                                       short* __restrict__ S1,
                                                       float* __restrict__ part_s,
                                                       float* __restrict__ part_s2) {
  __shared__ ushort act[4 * 66 * 128]; // 67584 B
  int bidx = blockIdx.x;
  int s = (bidx & 7) * 64 + (bidx >> 3);
  int b = s >> 5, y0 = (s & 31) << 1;
  int lane = threadIdx.x & 63, wave = threadIdx.x >> 6;
  int co0 = wave << 6;
  int l15 = lane & 15, lk = lane >> 4;

  f32x4 acc[4][8] = {};
  const uint4* h1g = (const uint4*)h1;
  uint4* a4 = (uint4*)act;
  const size_t abase = (size_t)((co0 + l15) << 5) + (lk << 3);

#define LOADAV(dst, ptr)                                                     \
  {                                                                          \
    _Pragma("unroll")                                                        \
    for (int ct_ = 0; ct_ < 4; ++ct_)                                        \
      dst[ct_] = *(const bf16x8*)((ptr) + abase + (ct_ << 9));               \
  }
#define KC_BLOCK(AV, kcv)                                                    \
  {                                                                          \
    _Pragma("unroll")                                                        \
    for (int r_ = 0; r_ < 2; ++r_) {                                         \
      bf16x8 Bv[4];                                                          \
      _Pragma("unroll")                                                      \
      for (int pt_ = 0; pt_ < 4; ++pt_) {                                    \
        int xi_ = (r_ + ty) * 66 + tx + pt_ * 16 + l15;                      \
        int u_ = (((xi_ << 4) + ((kcv) << 2) + lk) ^ (xi_ & 7));             \
        Bv[pt_] = *(bf16x8*)&act[u_ << 3];                                   \
      }                                                                      \
      _Pragma("unroll")                                                      \
      for (int ct_ = 0; ct_ < 4; ++ct_)                                      \
        _Pragma("unroll")                                                    \
        for (int pt_ = 0; pt_ < 4; ++pt_)                                    \
          acc[ct_][r_ * 4 + pt_] = __builtin_amdgcn_mfma_f32_16x16x32_bf16(  \
              AV[ct_], Bv[pt_], acc[ct_][r_ * 4 + pt_], 0, 0, 0);            \
    }                                                                        \
  }

  // stage 4 rows x 66 x 128ci: 4224 uint4, swizzled
  #pragma unroll 1
  for (int i = 0; i < 17; ++i) {
    int idx = i * 256 + threadIdx.x;
    if (idx < 4224) {
      int q = idx & 15, rowxz = idx >> 4;
      int xz = rowxz % 66, r = rowxz / 66;
      int yy = y0 + r - 1, xx = xz - 1;
      uint4 v = make_uint4(0, 0, 0, 0);
      if (((unsigned)yy < 64u) && ((unsigned)xx < 64u))
        v = h1g[(size_t)((b << 12) | (yy << 6) | xx) * 16 + q];
      a4[((rowxz << 4) + q) ^ (rowxz & 7)] = v;
    }
  }
  __syncthreads();

  bf16x8 AvA[4], AvB[4];
  LOADAV(AvA, wT1);
  #pragma unroll 1
  for (int tp = 0; tp < 9; ++tp) {
    int ty = tp / 3, tx = tp % 3;
    const ushort* wtp = wT1 + ((size_t)tp << 15);             // tp*4 slices * 8192
    const ushort* wnx = (tp < 8) ? (wtp + (1 << 15)) : wtp;

    LOADAV(AvB, wtp + (1 << 13));  KC_BLOCK(AvA, 0);
    LOADAV(AvA, wtp + (2 << 13));  KC_BLOCK(AvB, 1);
    LOADAV(AvB, wtp + (3 << 13));  KC_BLOCK(AvA, 2);
    LOADAV(AvA, wnx);              KC_BLOCK(AvB, 3);
  }
#undef LOADAV
#undef KC_BLOCK

  // epilogue: store S1 shorts
  #pragma unroll
  for (int ct = 0; ct < 4; ++ct)
    #pragma unroll
    for (int r = 0; r < 2; ++r)
      #pragma unroll
      for (int pt = 0; pt < 4; ++pt) {
        int x = pt * 16 + l15;
        short* ob = S1 + ((size_t)b << 20) + ((y0 + r) << 6) + x;
        #pragma unroll
        for (int j = 0; j < 4; ++j) {
          int co = co0 + ct * 16 + lk * 4 + j;
          ob[(size_t)co << 12] = (short)acc[ct][r * 4 + pt][j];
        }
      }
  // fused BN2 partials: per-co sum and sum-of-squares over this block's 128 px
  #pragma unroll
  for (int ct = 0; ct < 4; ++ct) {
    float s1v[4] = {0, 0, 0, 0}, s2v[4] = {0, 0, 0, 0};
    #pragma unroll
    for (int k = 0; k < 8; ++k)
      #pragma unroll
      for (int j = 0; j < 4; ++j) {
        float v = acc[ct][k][j];
        s1v[j] += v; s2v[j] += v * v;
      }
    #pragma unroll
    for (int off = 1; off < 16; off <<= 1)
      #pragma unroll
      for (int j = 0; j < 4; ++j) {
        s1v[j] += __shfl_xor(s1v[j], off);
        s2v[j] += __shfl_xor(s2v[j], off);
      }
    if (l15 == 0) {
      #pragma unroll
      for (int j = 0; j < 4; ++j) {
        int co = co0 + ct * 16 + lk * 4 + j;
        part_s[(size_t)s * 256 + co] = s1v[j];
        part_s2[(size_t)s * 256 + co] = s2v[j];
      }
    }
  }
}

// BN2 finalize from conv1's partials: y = a*s + c_b, c_b = b1 + temb[b]
__global__ void k_bn2_fin2(const float* __restrict__ part_s, const float* __restrict__ part_s2,
                           const float* __restrict__ al1, const float* __restrict__ b1,
                           const float* __restrict__ g2, const float* __restrict__ be2,
                           const float* __restrict__ temb,
                           float* __restrict__ A, float* __restrict__ Bc, float* __restrict__ Cc) {
  int co = blockIdx.x;  // 256
  int t = threadIdx.x;  // 64
  float sS = 0.f, scS = 0.f, s2 = 0.f;
  for (int k = 0; k < 8; ++k) {
    int blk = t + k * 64;
    int b = blk >> 5;
    float c = b1[co] + temb[(b << 8) + co];
    float Sv = part_s[(size_t)blk * 256 + co];
    sS += Sv; scS += c * Sv; s2 += part_s2[(size_t)blk * 256 + co];
  }
  #pragma unroll
  for (int off = 32; off > 0; off >>= 1) {
    sS += __shfl_down(sS, off); scS += __shfl_down(scS, off); s2 += __shfl_down(s2, off);
  }
  if (t == 0) {
    float a = al1[co];
    float sumc = 0.f, sumc2 = 0.f;
    for (int b = 0; b < 16; ++b) { float c = b1[co] + temb[(b << 8) + co]; sumc += c; sumc2 += c * c; }
    float sumY = a * sS + 4096.f * sumc;
    float sumY2 = a * a * s2 + 2.f * a * scS + 4096.f * sumc2;
    const float inv = 1.f / 65536.f;
    float m = sumY * inv, var = sumY2 * inv - m * m;
    float rs = rsqrtf(var + EPS);
    float gg = rs * g2[co];
    A[co] = a * gg;
    Bc[co] = (b1[co] - m) * gg + be2[co];
    Cc[co] = gg;
  }
}

// ---------------- fallback conv1 (popcount, R4-proven) ----------------
__global__ __launch_bounds__(256, 1) void k_conv1(const uint4* __restrict__ sbin, const uint* __restrict__ wb1,
                                                  const int* __restrict__ base1, short* __restrict__ S1) {
  __shared__ uint wlds[32 * 36];
  __shared__ int blds[9 * 32];
  int co0 = blockIdx.y << 5;
  #pragma unroll
  for (int k = 0; k < 4; ++k) wlds[k * 256 + threadIdx.x] = wb1[co0 * 36 + k * 256 + threadIdx.x];
  if (threadIdx.x < 128) wlds[1024 + threadIdx.x] = wb1[co0 * 36 + 1024 + threadIdx.x];
  #pragma unroll
  for (int k = 0; k < 2; ++k) {
    int idx = k * 256 + threadIdx.x;
    if (idx < 288) blds[idx] = base1[(idx >> 5) * 256 + co0 + (idx & 31)];
  }
  int bt = blockIdx.x;
  int b = bt >> 4;
  int y = ((bt & 15) << 2) | (threadIdx.x >> 6);
  int cx = threadIdx.x & 63;
  uint nb[9][4];
  #pragma unroll
  for (int dy = -1; dy <= 1; ++dy)
    #pragma unroll
    for (int dx = -1; dx <= 1; ++dx) {
      int tp = (dy + 1) * 3 + (dx + 1);
      int yy = y + dy, xx = cx + dx;
      bool v = ((unsigned)yy < 64u) && ((unsigned)xx < 64u);
      uint4 q = make_uint4(0, 0, 0, 0);
      if (v) q = sbin[(b << 12) | (yy << 6) | xx];
      nb[tp][0] = q.x; nb[tp][1] = q.y; nb[tp][2] = q.z; nb[tp][3] = q.w;
    }
  int pat = ((y == 0) ? 0 : ((y == 63) ? 6 : 3)) + ((cx == 0) ? 0 : ((cx == 63) ? 2 : 1));
  __syncthreads();
  int p = (y << 6) | cx;
  short* op = S1 + ((size_t)b << 20) + ((size_t)co0 << 12) + p;
  #pragma unroll 1
  for (int cc = 0; cc < 4; ++cc) {
    short accv[8];
    #pragma unroll
    for (int j = 0; j < 8; ++j) {
      int co_l = cc * 8 + j;
      const uint4* wp4 = (const uint4*)(wlds + co_l * 36);
      uint m0 = 0, m1 = 0, m2 = 0, m3 = 0;
      #pragma unroll
      for (int tp = 0; tp < 9; ++tp) {
        uint4 w4 = wp4[tp];
        m0 += __popc(nb[tp][0] ^ w4.x);
        m1 += __popc(nb[tp][1] ^ w4.y);
        m2 += __popc(nb[tp][2] ^ w4.z);
        m3 += __popc(nb[tp][3] ^ w4.w);
      }
      accv[j] = (short)(blds[pat * 32 + co_l] - 2 * (int)((m0 + m1) + (m2 + m3)));
    }
    #pragma unroll
    for (int j = 0; j < 8; ++j) op[(size_t)(cc * 8 + j) << 12] = accv[j];
  }
}

// ---------------- fallback BN2 stats ----------------
__global__ __launch_bounds__(256) void k_bn2_part(const short* __restrict__ S1, const float* __restrict__ al1,
                                                  const float* __restrict__ b1, const float* __restrict__ temb,
                                                  float* __restrict__ part) {
  int co = blockIdx.x, chunk = blockIdx.y;
  float a = al1[co], bb = b1[co];
  float s = 0.f, s2 = 0.f;
  #pragma unroll
  for (int jb = 0; jb < 2; ++jb) {
    int b = chunk * 2 + jb;
    float tb_ = bb + temb[(b << 8) | co];
    const uint4* sp = (const uint4*)(S1 + ((size_t)b << 20) + ((size_t)co << 12));
    #pragma unroll
    for (int k = 0; k < 2; ++k) {
      uint4 q = sp[k * 256 + threadIdx.x];
      uint ws[4] = {q.x, q.y, q.z, q.w};
      #pragma unroll
      for (int w = 0; w < 4; ++w) {
        float f0 = fmaf(a, (float)((short)(ws[w] & 0xffffu)), tb_);
        float f1 = fmaf(a, (float)((short)(ws[w] >> 16)), tb_);
        s += f0 + f1;
        s2 += f0 * f0 + f1 * f1;
      }
    }
  }
  #pragma unroll
  for (int off = 32; off > 0; off >>= 1) { s += __shfl_down(s, off); s2 += __shfl_down(s2, off); }
  __shared__ float ls[4], ls2[4];
  int wid = threadIdx.x >> 6, lane = threadIdx.x & 63;
  if (lane == 0) { ls[wid] = s; ls2[wid] = s2; }
  __syncthreads();
  if (threadIdx.x == 0) {
    part[(co * 8 + chunk) * 2 + 0] = ls[0] + ls[1] + ls[2] + ls[3];
    part[(co * 8 + chunk) * 2 + 1] = ls2[0] + ls2[1] + ls2[2] + ls2[3];
  }
}

__global__ void k_bn2_fin(const float* __restrict__ part, const float* __restrict__ al1,
                          const float* __restrict__ b1, const float* __restrict__ g2,
                          const float* __restrict__ be2, float* __restrict__ A,
                          float* __restrict__ Bc, float* __restrict__ Cc) {
  int co = threadIdx.x;
  float s = 0.f, s2 = 0.f;
  for (int k = 0; k < 8; ++k) { s += part[(co * 8 + k) * 2]; s2 += part[(co * 8 + k) * 2 + 1]; }
  const float inv = 1.f / 65536.f;
  float m = s * inv, var = s2 * inv - m * m;
  float rs = rsqrtf(var + EPS);
  float gg = rs * g2[co];
  A[co] = al1[co] * gg;
  Bc[co] = (b1[co] - m) * gg + be2[co];
  Cc[co] = gg;
}

// ---------------- binarize2 -> bf16 +-1, layout [b][px][256ci] (MFMA path) ----------------
__global__ __launch_bounds__(256) void k_bin2_bf16(const short* __restrict__ S1, const float* __restrict__ A,
                                                   const float* __restrict__ Bc, const float* __restrict__ Cc,
                                                   const float* __restrict__ temb, uint4* __restrict__ h2u4) {
  __shared__ uint4 tile[64 * 32];
  int b = blockIdx.x >> 6;
  int px0 = (blockIdx.x & 63) << 6;
  int pxl = threadIdx.x & 63, quad = threadIdx.x >> 6;
  const short* sp = S1 + ((size_t)b << 20) + (px0 + pxl);
  const float* tp = temb + (b << 8);
  #pragma unroll 1
  for (int g = 0; g < 8; ++g) {
    uint d[4];
    #pragma unroll
    for (int h = 0; h < 4; ++h) {
      int c0 = quad * 64 + g * 8 + h * 2;
      float v0 = A[c0] * (float)sp[(size_t)c0 << 12] + Bc[c0] + Cc[c0] * tp[c0];
      float v1 = A[c0 + 1] * (float)sp[(size_t)(c0 + 1) << 12] + Bc[c0 + 1] + Cc[c0 + 1] * tp[c0 + 1];
      uint s0 = (v0 > 0.f) ? 0x3F80u : 0xBF80u;
      uint s1 = (v1 > 0.f) ? 0x3F80u : 0xBF80u;
      d[h] = s0 | (s1 << 16);
    }
    int slot = quad * 8 + g;
    tile[pxl * 32 + (slot ^ (pxl & 7))] = make_uint4(d[0], d[1], d[2], d[3]);
  }
  __syncthreads();
  uint4* dst = h2u4 + ((size_t)(b << 12) + px0) * 32;
  #pragma unroll
  for (int k = 0; k < 8; ++k) {
    int c = k * 256 + threadIdx.x;
    int px = c >> 5, slot = c & 31;
    dst[c] = tile[px * 32 + (slot ^ (px & 7))];
  }
}

// ---------------- conv2 MFMA v5 (R10-proven) ----------------
__global__ __launch_bounds__(256, 2) void k_conv2_mfma(const ushort* __restrict__ h2,
                                                       const ushort* __restrict__ wT,
                                                       const float* __restrict__ al2,
                                                       float* __restrict__ out) {
  __shared__ ushort act[4 * 66 * 128];
  int bidx = blockIdx.x;
  int s = (bidx & 7) * 64 + (bidx >> 3);
  int b = s >> 5, y0 = (s & 31) << 1;
  int lane = threadIdx.x & 63, wave = threadIdx.x >> 6;
  int co0 = wave << 6;
  int l15 = lane & 15, lk = lane >> 4;

  f32x4 acc[4][8] = {};
  const uint4* h2g = (const uint4*)h2;
  uint4* a4 = (uint4*)act;
  const size_t abase = (size_t)((co0 + l15) << 5) + (lk << 3);

#define LOADAV(dst, ptr)                                                     \
  {                                                                          \
    _Pragma("unroll")                                                        \
    for (int ct_ = 0; ct_ < 4; ++ct_)                                        \
      dst[ct_] = *(const bf16x8*)((ptr) + abase + (ct_ << 9));               \
  }
#define KC_BLOCK(AV, kcv)                                                    \
  {                                                                          \
    _Pragma("unroll")                                                        \
    for (int r_ = 0; r_ < 2; ++r_) {                                         \
      bf16x8 Bv[4];                                                          \
      _Pragma("unroll")                                                      \
      for (int pt_ = 0; pt_ < 4; ++pt_) {                                    \
        int xi_ = (r_ + ty) * 66 + tx + pt_ * 16 + l15;                      \
        int u_ = (((xi_ << 4) + ((kcv) << 2) + lk) ^ (xi_ & 7));             \
        Bv[pt_] = *(bf16x8*)&act[u_ << 3];                                   \
      }                                                                      \
      _Pragma("unroll")                                                      \
      for (int ct_ = 0; ct_ < 4; ++ct_)                                      \
        _Pragma("unroll")                                                    \
        for (int pt_ = 0; pt_ < 4; ++pt_)                                    \
          acc[ct_][r_ * 4 + pt_] = __builtin_amdgcn_mfma_f32_16x16x32_bf16(  \
              AV[ct_], Bv[pt_], acc[ct_][r_ * 4 + pt_], 0, 0, 0);            \
    }                                                                        \
  }

  #pragma unroll 1
  for (int chunk = 0; chunk < 2; ++chunk) {
    if (chunk) __syncthreads();
    #pragma unroll 1
    for (int i = 0; i < 17; ++i) {
      int idx = i * 256 + threadIdx.x;
      if (idx < 4224) {
        int q = idx & 15, rowxz = idx >> 4;
        int xz = rowxz % 66, r = rowxz / 66;
        int yy = y0 + r - 1, xx = xz - 1;
        uint4 v = make_uint4(0, 0, 0, 0);
        if (((unsigned)yy < 64u) && ((unsigned)xx < 64u))
          v = h2g[(size_t)((b << 12) | (yy << 6) | xx) * 32 + chunk * 16 + q];
        a4[((rowxz << 4) + q) ^ (rowxz & 7)] = v;
      }
    }
    __syncthreads();

    const ushort* wch = wT + ((size_t)chunk << 15);
    bf16x8 AvA[4], AvB[4];
    LOADAV(AvA, wch);

    #pragma unroll 1
    for (int tp = 0; tp < 9; ++tp) {
      int ty = tp / 3, tx = tp % 3;
      const ushort* wtp = wch + ((size_t)tp << 16);
      const ushort* wnx = (tp < 8) ? (wtp + (1 << 16)) : wtp;

      LOADAV(AvB, wtp + (1 << 13));  KC_BLOCK(AvA, 0);
      LOADAV(AvA, wtp + (2 << 13));  KC_BLOCK(AvB, 1);
      LOADAV(AvB, wtp + (3 << 13));  KC_BLOCK(AvA, 2);
      LOADAV(AvA, wnx);              KC_BLOCK(AvB, 3);
    }
  }
#undef LOADAV
#undef KC_BLOCK

  #pragma unroll
  for (int ct = 0; ct < 4; ++ct) {
    #pragma unroll
    for (int r = 0; r < 2; ++r) {
      #pragma unroll
      for (int pt = 0; pt < 4; ++pt) {
        int x = pt * 16 + l15;
        float* ob = out + ((size_t)b << 20) + ((y0 + r) << 6) + x;
        #pragma unroll
        for (int j = 0; j < 4; ++j) {
          int co = co0 + ct * 16 + lk * 4 + j;
          float* p = ob + ((size_t)co << 12);
          *p = fmaf(al2[co], acc[ct][r * 4 + pt][j], *p);
        }
      }
    }
  }
}

// ---------------- fallback conv2 path ----------------
__global__ __launch_bounds__(256) void k_bin2_packed(const short* __restrict__ S1, const float* __restrict__ A,
                                                     const float* __restrict__ Bc, const float* __restrict__ Cc,
                                                     const float* __restrict__ temb, uint4* __restrict__ hbin) {
  int pg = blockIdx.x * 256 + threadIdx.x;
  int b = pg >> 12, p = pg & 4095;
  int c0 = blockIdx.y << 7;
  const short* sp = S1 + ((size_t)b << 20) + p;
  const float* tp = temb + (b << 8);
  uint w[4];
  #pragma unroll
  for (int wd = 0; wd < 4; ++wd) {
    uint acc = 0;
    #pragma unroll
    for (int i = 0; i < 32; ++i) {
      int co = c0 + wd * 32 + i;
      float v = A[co] * (float)sp[(size_t)co << 12] + Bc[co] + Cc[co] * tp[co];
      acc |= (v > 0.f ? 1u : 0u) << i;
    }
    w[wd] = acc;
  }
  hbin[pg * 2 + blockIdx.y] = make_uint4(w[0], w[1], w[2], w[3]);
}

__global__ __launch_bounds__(256, 1) void k_conv2_pop(const uint4* __restrict__ hbin, const uint* __restrict__ wb2,
                                                      const int* __restrict__ base2, const float* __restrict__ al2,
                                                      float* __restrict__ out) {
  __shared__ uint wlds[32 * 72];
  __shared__ int blds[9 * 32];
  int co0 = blockIdx.y << 5;
  #pragma unroll
  for (int k = 0; k < 9; ++k) wlds[k * 256 + threadIdx.x] = wb2[co0 * 72 + k * 256 + threadIdx.x];
  #pragma unroll
  for (int k = 0; k < 2; ++k) {
    int idx = k * 256 + threadIdx.x;
    if (idx < 288) blds[idx] = base2[(idx >> 5) * 256 + co0 + (idx & 31)];
  }
  int bt = blockIdx.x;
  int b = bt >> 4;
  int y = ((bt & 15) << 2) | (threadIdx.x >> 6);
  int cx = threadIdx.x & 63;
  uint nb[9][8];
  #pragma unroll
  for (int dy = -1; dy <= 1; ++dy)
    #pragma unroll
    for (int dx = -1; dx <= 1; ++dx) {
      int tp = (dy + 1) * 3 + (dx + 1);
      int yy = y + dy, xx = cx + dx;
      bool v = ((unsigned)yy < 64u) && ((unsigned)xx < 64u);
      uint4 q0 = make_uint4(0, 0, 0, 0), q1 = make_uint4(0, 0, 0, 0);
      if (v) {
        int pix = (b << 12) | (yy << 6) | xx;
        q0 = hbin[pix * 2 + 0];
        q1 = hbin[pix * 2 + 1];
      }
      nb[tp][0] = q0.x; nb[tp][1] = q0.y; nb[tp][2] = q0.z; nb[tp][3] = q0.w;
      nb[tp][4] = q1.x; nb[tp][5] = q1.y; nb[tp][6] = q1.z; nb[tp][7] = q1.w;
    }
  int pat = ((y == 0) ? 0 : ((y == 63) ? 6 : 3)) + ((cx == 0) ? 0 : ((cx == 63) ? 2 : 1));
  __syncthreads();
  int p = (y << 6) | cx;
  float* op = out + ((size_t)b << 20) + ((size_t)co0 << 12) + p;
  #pragma unroll 1
  for (int cc = 0; cc < 4; ++cc) {
    float ov[8];
    #pragma unroll
    for (int j = 0; j < 8; ++j) ov[j] = op[(size_t)(cc * 8 + j) << 12];
    #pragma unroll
    for (int j = 0; j < 8; ++j) {
      int co_l = cc * 8 + j;
      const uint4* wp4 = (const uint4*)(wlds + co_l * 72);
      uint m0 = 0, m1 = 0, m2 = 0, m3 = 0;
      #pragma unroll
      for (int tp = 0; tp < 9; ++tp) {
        uint4 wa = wp4[tp * 2 + 0];
        uint4 wb_ = wp4[tp * 2 + 1];
        m0 += __popc(nb[tp][0] ^ wa.x);
        m1 += __popc(nb[tp][1] ^ wa.y);
        m2 += __popc(nb[tp][2] ^ wa.z);
        m3 += __popc(nb[tp][3] ^ wa.w);
        m0 += __popc(nb[tp][4] ^ wb_.x);
        m1 += __popc(nb[tp][5] ^ wb_.y);
        m2 += __popc(nb[tp][6] ^ wb_.z);
        m3 += __popc(nb[tp][7] ^ wb_.w);
      }
      int acc = blds[pat * 32 + co_l] - 2 * (int)((m0 + m1) + (m2 + m3));
      ov[j] = fmaf(al2[co0 + co_l], (float)acc, ov[j]);
    }
    #pragma unroll
    for (int j = 0; j < 8; ++j) op[(size_t)(cc * 8 + j) << 12] = ov[j];
  }
}

extern "C" void kernel_launch(void* const* d_in, const int* in_sizes, int n_in,
                              void* d_out, int out_size, void* d_ws, size_t ws_size,
                              hipStream_t stream) {
  const float* x    = (const float*)d_in[0];
  const float* t    = (const float*)d_in[1];
  const float* bn1g = (const float*)d_in[2];
  const float* bn1b = (const float*)d_in[3];
  const float* w1   = (const float*)d_in[4];
  const float* b1   = (const float*)d_in[5];
  const float* tW   = (const float*)d_in[6];
  const float* tb   = (const float*)d_in[7];
  const float* bn2g = (const float*)d_in[8];
  const float* bn2b = (const float*)d_in[9];
  const float* w2   = (const float*)d_in[10];
  const float* b2   = (const float*)d_in[11];
  const float* wsk  = (const float*)d_in[12];
  const float* bsk  = (const float*)d_in[13];
  float* out = (float*)d_out;
  char* ws = (char*)d_ws;

  float* bn1part = (float*)(ws + 0);
  float* sc1     = (float*)(ws + 8192);
  float* sh1     = (float*)(ws + 8704);
  uint4* sbin    = (uint4*)(ws + 9216);      // 1 MB (fallback bin1)
  uint*  wb1     = (uint*) (ws + 1057792);
  float* al1     = (float*)(ws + 1094656);
  uint*  wb2     = (uint*) (ws + 1095680);
  float* al2     = (float*)(ws + 1169408);
  float* swkT    = (float*)(ws + 1170432);
  float* temb    = (float*)(ws + 1301504);
  float* bn2part = (float*)(ws + 1317888);
  float* A2      = (float*)(ws + 1334272);
  float* Bc2     = (float*)(ws + 1335296);
  float* Cc2     = (float*)(ws + 1336320);
  int*   base1g  = (int*)  (ws + 1337344);
  int*   base2g  = (int*)  (ws + 1346560);
  // region 1355776..3452928 shared: hbin (fallback conv2) OR part_s/part_s2+wT1 (mfma path)
  uint4*  hbin    = (uint4*)(ws + 1355776);  // 2 MB
  float*  part_s  = (float*)(ws + 1355776);  // 512 KB
  float*  part_s2 = (float*)(ws + 1880064);  // 512 KB
  ushort* wT1     = (ushort*)(ws + 2404352); // 590 KB
  ushort* wT2     = (ushort*)(ws + 3452928); // 1.18 MB
  short*  S1      = (short*)(ws + 4632576);  // 33.5 MB
  ushort* h2      = (ushort*)(ws + 38187008);// 33.5 MB
  ushort* h1      = (ushort*)(ws + 71741440);// 16.8 MB -> end 88518656
  const size_t WS_NEED2 = 71741440ULL;
  const size_t WS_NEED1 = 88518656ULL;
  bool mode2 = (ws_size >= WS_NEED2);
  bool mode1 = (ws_size >= WS_NEED1);

  k_bn1_part<<<dim3(128, 8), 256, 0, stream>>>(x, bn1part);
  k_bn1_fin<<<1, 128, 0, stream>>>(bn1part, bn1g, bn1b, sc1, sh1);
  k_packw1<<<256, 128, 0, stream>>>(w1, wb1, al1, wT1);
  k_packw2<<<256, 256, 0, stream>>>(w2, wb2, al2, wT2);
  k_base<<<1, 256, 0, stream>>>(wb1, wb2, base1g, base2g);
  k_packws<<<256, 128, 0, stream>>>(wsk, swkT);
  k_temb<<<16, 256, 0, stream>>>(t, tW, tb, temb);
  k_skip<<<dim3(1024, 4), 256, 0, stream>>>(x, swkT, bsk, b2, sc1, sh1, (uint*)sbin, h1,
                                            mode1 ? 1 : 0, out);
  if (mode1) {
    k_conv1_mfma<<<512, 256, 0, stream>>>(h1, wT1, S1, part_s, part_s2);
    k_bn2_fin2<<<256, 64, 0, stream>>>(part_s, part_s2, al1, b1, bn2g, bn2b, temb, A2, Bc2, Cc2);
  } else {
    k_conv1<<<dim3(256, 8), 256, 0, stream>>>(sbin, wb1, base1g, S1);
    k_bn2_part<<<dim3(256, 8), 256, 0, stream>>>(S1, al1, b1, temb, bn2part);
    k_bn2_fin<<<1, 256, 0, stream>>>(bn2part, al1, b1, bn2g, bn2b, A2, Bc2, Cc2);
  }
  if (mode2) {
    k_bin2_bf16<<<1024, 256, 0, stream>>>(S1, A2, Bc2, Cc2, temb, (uint4*)h2);
    k_conv2_mfma<<<512, 256, 0, stream>>>(h2, wT2, al2, out);
  } else {
    k_bin2_packed<<<dim3(256, 2), 256, 0, stream>>>(S1, A2, Bc2, Cc2, temb, hbin);
    k_conv2_pop<<<dim3(256, 8), 256, 0, stream>>>(hbin, wb2, base2g, al2, out);
  }
}

// Round 13
// 226.972 us; speedup vs baseline: 2.1153x; 1.0208x over previous
//
#include <hip/hip_runtime.h>
#include <stdint.h>

typedef unsigned int uint;
typedef short bf16x8 __attribute__((ext_vector_type(8)));
typedef float f32x4 __attribute__((ext_vector_type(4)));

#define EPS 1e-5f

// Shapes: B=16, Cin=128, Cout=256, T=512, H=W=64, HW=4096, NPIX=65536

// ---------------- BN1 stats ----------------
__global__ __launch_bounds__(256) void k_bn1_part(const float* __restrict__ x, float* __restrict__ part) {
  int c = blockIdx.x, chunk = blockIdx.y;
  float s = 0.f, s2 = 0.f;
  #pragma unroll
  for (int jb = 0; jb < 2; ++jb) {
    int b = chunk * 2 + jb;
    const float4* xb = (const float4*)(x + (((size_t)((b << 7) | c)) << 12));
    #pragma unroll
    for (int k = 0; k < 4; ++k) {
      float4 q = xb[k * 256 + threadIdx.x];
      s += (q.x + q.y) + (q.z + q.w);
      s2 += q.x * q.x + q.y * q.y + q.z * q.z + q.w * q.w;
    }
  }
  #pragma unroll
  for (int off = 32; off > 0; off >>= 1) { s += __shfl_down(s, off); s2 += __shfl_down(s2, off); }
  __shared__ float ls[4], ls2[4];
  int wid = threadIdx.x >> 6, lane = threadIdx.x & 63;
  if (lane == 0) { ls[wid] = s; ls2[wid] = s2; }
  __syncthreads();
  if (threadIdx.x == 0) {
    part[(c * 8 + chunk) * 2 + 0] = ls[0] + ls[1] + ls[2] + ls[3];
    part[(c * 8 + chunk) * 2 + 1] = ls2[0] + ls2[1] + ls2[2] + ls2[3];
  }
}

__global__ void k_bn1_fin(const float* __restrict__ part, const float* __restrict__ g,
                          const float* __restrict__ be, float* __restrict__ sc, float* __restrict__ sh) {
  int c = threadIdx.x;
  float s = 0.f, s2 = 0.f;
  for (int k = 0; k < 8; ++k) { s += part[(c * 8 + k) * 2]; s2 += part[(c * 8 + k) * 2 + 1]; }
  const float inv = 1.f / 65536.f;
  float m = s * inv, var = s2 * inv - m * m;
  float rs = rsqrtf(var + EPS);
  float scale = rs * g[c];
  sc[c] = scale;
  sh[c] = be[c] - m * scale;
}

// ---------------- weight packing ----------------
// also emits bf16 sign weights transposed: wT1[slice=(tp*4+kc)][co][32ci]
__global__ __launch_bounds__(128) void k_packw1(const float* __restrict__ w1, uint* __restrict__ wb,
                                                float* __restrict__ alpha, ushort* __restrict__ wT1) {
  int co = blockIdx.x, wid = threadIdx.x >> 6, lane = threadIdx.x & 63;
  int ci = threadIdx.x;
  const float* wp = w1 + (co * 128 + ci) * 9;
  float wv[9]; float s = 0.f;
  #pragma unroll
  for (int tp = 0; tp < 9; ++tp) { wv[tp] = wp[tp]; s += fabsf(wv[tp]); }
  #pragma unroll
  for (int tp = 0; tp < 9; ++tp) {
    wT1[(((tp << 2) + (ci >> 5)) << 13) + (co << 5) + (ci & 31)] = (wv[tp] > 0.f) ? 0x3F80u : 0xBF80u;
    unsigned long long m = __ballot(wv[tp] > 0.f);
    if (lane == 0) {
      wb[(co * 9 + tp) * 4 + wid * 2 + 0] = (uint)m;
      wb[(co * 9 + tp) * 4 + wid * 2 + 1] = (uint)(m >> 32);
    }
  }
  #pragma unroll
  for (int off = 32; off > 0; off >>= 1) s += __shfl_down(s, off);
  __shared__ float l2[2];
  if (lane == 0) l2[wid] = s;
  __syncthreads();
  if (threadIdx.x == 0) alpha[co] = (l2[0] + l2[1]) * (1.f / 1152.f);
}

// emits bf16 sign weights TRANSPOSED for MFMA: wT[slice=(tap*8+chunk*4+kc)][co][32ci_local]
__global__ __launch_bounds__(256) void k_packw2(const float* __restrict__ w2, uint* __restrict__ wb,
                                                float* __restrict__ alpha, ushort* __restrict__ wT) {
  int co = blockIdx.x, wid = threadIdx.x >> 6, lane = threadIdx.x & 63;
  int ci = threadIdx.x;
  const float* wp = w2 + (co * 256 + ci) * 9;
  float wv[9]; float s = 0.f;
  #pragma unroll
  for (int tp = 0; tp < 9; ++tp) { wv[tp] = wp[tp]; s += fabsf(wv[tp]); }
  int chunk = ci >> 7, kc = (ci >> 5) & 3, cil = ci & 31;
  #pragma unroll
  for (int tp = 0; tp < 9; ++tp) {
    wT[(((tp << 3) + (chunk << 2) + kc) << 13) + (co << 5) + cil] = (wv[tp] > 0.f) ? 0x3F80u : 0xBF80u;
    unsigned long long m = __ballot(wv[tp] > 0.f);
    if (lane == 0) {
      wb[(co * 9 + tp) * 8 + wid * 2 + 0] = (uint)m;
      wb[(co * 9 + tp) * 8 + wid * 2 + 1] = (uint)(m >> 32);
    }
  }
  #pragma unroll
  for (int off = 32; off > 0; off >>= 1) s += __shfl_down(s, off);
  __shared__ float l4[4];
  if (lane == 0) l4[wid] = s;
  __syncthreads();
  if (threadIdx.x == 0) alpha[co] = (l4[0] + l4[1] + l4[2] + l4[3]) * (1.f / 2304.f);
}

__global__ __launch_bounds__(256) void k_base(const uint* __restrict__ wb1, const uint* __restrict__ wb2,
                                              int* __restrict__ base1, int* __restrict__ base2) {
  int co = threadIdx.x;
  int pc1[9], pc2[9];
  #pragma unroll
  for (int tp = 0; tp < 9; ++tp) {
    uint a = 0;
    #pragma unroll
    for (int k = 0; k < 4; ++k) a += __popc(wb1[co * 36 + tp * 4 + k]);
    pc1[tp] = (int)a;
    uint b = 0;
    #pragma unroll
    for (int k = 0; k < 8; ++k) b += __popc(wb2[co * 72 + tp * 8 + k]);
    pc2[tp] = (int)b;
  }
  #pragma unroll
  for (int pat = 0; pat < 9; ++pat) {
    int yt = pat / 3, xt = pat % 3;
    int b1v = 1152, b2v = 2304;
    #pragma unroll
    for (int tp = 0; tp < 9; ++tp) {
      int dy = tp / 3 - 1, dx = tp % 3 - 1;
      bool inv = (dy < 0 && yt == 0) || (dy > 0 && yt == 2) || (dx < 0 && xt == 0) || (dx > 0 && xt == 2);
      if (inv) { b1v -= 128 - 2 * pc1[tp]; b2v -= 256 - 2 * pc2[tp]; }
    }
    base1[pat * 256 + co] = b1v;
    base2[pat * 256 + co] = b2v;
  }
}

__global__ __launch_bounds__(128) void k_packws(const float* __restrict__ wsk, float* __restrict__ swT) {
  int co = blockIdx.x, ci = threadIdx.x;
  float v = wsk[co * 128 + ci];
  float s = fabsf(v);
  #pragma unroll
  for (int off = 32; off > 0; off >>= 1) s += __shfl_down(s, off);
  __shared__ float l2[2]; __shared__ float tot;
  int wid = threadIdx.x >> 6, lane = threadIdx.x & 63;
  if (lane == 0) l2[wid] = s;
  __syncthreads();
  if (threadIdx.x == 0) tot = (l2[0] + l2[1]) * (1.f / 128.f);
  __syncthreads();
  float a = tot;
  swT[ci * 256 + co] = (v > 0.f) ? a : -a;
}

// ---------------- temb ----------------
__global__ __launch_bounds__(256) void k_temb(const float* __restrict__ t, const float* __restrict__ tW,
                                              const float* __restrict__ tbias, float* __restrict__ temb) {
  int b = blockIdx.x, co = threadIdx.x;
  const float* tr = t + b * 512;
  const float* wr = tW + co * 512;
  float a0 = 0, a1 = 0, a2 = 0, a3 = 0;
  #pragma unroll 8
  for (int k = 0; k < 512; k += 4) {
    a0 = fmaf(tr[k + 0], wr[k + 0], a0);
    a1 = fmaf(tr[k + 1], wr[k + 1], a1);
    a2 = fmaf(tr[k + 2], wr[k + 2], a2);
    a3 = fmaf(tr[k + 3], wr[k + 3], a3);
  }
  temb[b * 256 + co] = (a0 + a1) + (a2 + a3) + tbias[co];
}

// ---------------- skip GEMM v2: 8x8 micro-tile, K-chunked, swizzled x-tile + fused bin1 ----------------
// Block = 128px x 128co; grid (512, 2). LDS traffic 1 B/FMA (vs 2 in v1).
__global__ __launch_bounds__(256, 2) void k_skip(const float* __restrict__ x, const float* __restrict__ swT,
                                                 const float* __restrict__ bsk, const float* __restrict__ b2,
                                                 const float* __restrict__ sc1, const float* __restrict__ sh1,
                                                 uint* __restrict__ sbinw, ushort* __restrict__ h1w,
                                                 int mfma1, float* __restrict__ out) {
  __shared__ float xs[32 * 136];   // [ci][128px swizzled: g*8+(g>>2)*2+(px&7)] 17.4 KB
  __shared__ float wsl[32 * 128];  // [ci][co] 16.4 KB
  int s = blockIdx.x;
  int b = s >> 5;
  int px0 = (s & 31) << 7;
  int co0 = blockIdx.y << 7;
  int t = threadIdx.x;
  int tx = t & 15, ty = t >> 4;

  float4 acc[8][2];
  #pragma unroll
  for (int i = 0; i < 8; ++i) { acc[i][0] = make_float4(0, 0, 0, 0); acc[i][1] = make_float4(0, 0, 0, 0); }

  #pragma unroll 1
  for (int kc = 0; kc < 4; ++kc) {
    if (kc) __syncthreads();
    // stage x: 32ci x 128px (swizzled groups -> 16 distinct banks on read)
    #pragma unroll
    for (int k2 = 0; k2 < 4; ++k2) {
      int idx = k2 * 256 + t;
      int ci_l = idx >> 5, pxl = (idx & 31) << 2;
      float4 v = *(const float4*)(x + (((size_t)((b << 7) | (kc * 32 + ci_l))) << 12) + px0 + pxl);
      int g = pxl >> 3;
      *(float4*)&xs[ci_l * 136 + g * 8 + ((g >> 2) << 1) + (pxl & 7)] = v;
    }
    // stage w: 32ci x 128co
    #pragma unroll
    for (int k2 = 0; k2 < 4; ++k2) {
      int idx = k2 * 256 + t;
      int ci_l = idx >> 5, col = (idx & 31) << 2;
      *(float4*)&wsl[ci_l * 128 + col] = *(const float4*)(swT + (size_t)(kc * 32 + ci_l) * 256 + co0 + col);
    }
    __syncthreads();

    // fused bin1 for this ci-chunk (one co-block only)
    if (blockIdx.y == 0 && t < 128) {
      int pxl = t;
      int g = pxl >> 3;
      int xo = g * 8 + ((g >> 2) << 1) + (pxl & 7);
      if (mfma1) {
        ushort hv[32];
        #pragma unroll
        for (int i = 0; i < 32; ++i) {
          int ci = kc * 32 + i;
          float v = xs[i * 136 + xo];
          hv[i] = ((v * sc1[ci] + sh1[ci]) > 0.f) ? (ushort)0x3F80u : (ushort)0xBF80u;
        }
        uint4* dst = (uint4*)(h1w + (((size_t)((b << 12) | (px0 + pxl))) << 7) + (kc << 5));
        const uint4* srcv = (const uint4*)hv;
        dst[0] = srcv[0]; dst[1] = srcv[1]; dst[2] = srcv[2]; dst[3] = srcv[3];
      } else {
        uint accb = 0;
        #pragma unroll
        for (int i = 0; i < 32; ++i) {
          int ci = kc * 32 + i;
          float v = xs[i * 136 + xo];
          accb |= ((v * sc1[ci] + sh1[ci]) > 0.f ? 1u : 0u) << i;
        }
        sbinw[(((size_t)b << 12) | (px0 + pxl)) * 4 + kc] = accb;
      }
    }

    int xbase = tx * 8 + ((tx >> 2) << 1);
    int wbase = ty * 8;
    #pragma unroll 2
    for (int ci = 0; ci < 32; ++ci) {
      float4 xv0 = *(float4*)&xs[ci * 136 + xbase];
      float4 xv1 = *(float4*)&xs[ci * 136 + xbase + 4];
      float4 wv0 = *(float4*)&wsl[ci * 128 + wbase];
      float4 wv1 = *(float4*)&wsl[ci * 128 + wbase + 4];
      float wq[8] = {wv0.x, wv0.y, wv0.z, wv0.w, wv1.x, wv1.y, wv1.z, wv1.w};
      #pragma unroll
      for (int i = 0; i < 8; ++i) {
        acc[i][0].x = fmaf(wq[i], xv0.x, acc[i][0].x);
        acc[i][0].y = fmaf(wq[i], xv0.y, acc[i][0].y);
        acc[i][0].z = fmaf(wq[i], xv0.z, acc[i][0].z);
        acc[i][0].w = fmaf(wq[i], xv0.w, acc[i][0].w);
        acc[i][1].x = fmaf(wq[i], xv1.x, acc[i][1].x);
        acc[i][1].y = fmaf(wq[i], xv1.y, acc[i][1].y);
        acc[i][1].z = fmaf(wq[i], xv1.z, acc[i][1].z);
        acc[i][1].w = fmaf(wq[i], xv1.w, acc[i][1].w);
      }
    }
  }

  // epilogue: out = acc + (bsk + b2)
  float* ob = out + ((size_t)b << 20) + px0 + tx * 8;
  #pragma unroll
  for (int i = 0; i < 8; ++i) {
    int co = co0 + ty * 8 + i;
    float bb = bsk[co] + b2[co];
    float4 r0 = acc[i][0]; r0.x += bb; r0.y += bb; r0.z += bb; r0.w += bb;
    float4 r1 = acc[i][1]; r1.x += bb; r1.y += bb; r1.z += bb; r1.w += bb;
    *(float4*)(ob + ((size_t)co << 12)) = r0;
    *(float4*)(ob + ((size_t)co << 12) + 4) = r1;
  }
}

// ---------------- conv1 MFMA: S1 = Wsgn1 conv h1, + fused BN2 partial sums ----------------
__global__ __launch_bounds__(256, 2) void k_conv1_mfma(const ushort* __restrict__ h1,
                                                       const ushort* __restrict__ wT1,
                                                       short* __restrict__ S1,
                                                       float* __restrict__ part_s,
                                                       float* __restrict__ part_s2) {
  __shared__ ushort act[4 * 66 * 128]; // 67584 B
  int bidx = blockIdx.x;
  int s = (bidx & 7) * 64 + (bidx >> 3);
  int b = s >> 5, y0 = (s & 31) << 1;
  int lane = threadIdx.x & 63, wave = threadIdx.x >> 6;
  int co0 = wave << 6;
  int l15 = lane & 15, lk = lane >> 4;

  f32x4 acc[4][8] = {};
  const uint4* h1g = (const uint4*)h1;
  uint4* a4 = (uint4*)act;
  const size_t abase = (size_t)((co0 + l15) << 5) + (lk << 3);

#define LOADAV(dst, ptr)                                                     \
  {                                                                          \
    _Pragma("unroll")                                                        \
    for (int ct_ = 0; ct_ < 4; ++ct_)                                        \
      dst[ct_] = *(const bf16x8*)((ptr) + abase + (ct_ << 9));               \
  }
#define KC_BLOCK(AV, kcv)                                                    \
  {                                                                          \
    _Pragma("unroll")                                                        \
    for (int r_ = 0; r_ < 2; ++r_) {                                         \
      bf16x8 Bv[4];                                                          \
      _Pragma("unroll")                                                      \
      for (int pt_ = 0; pt_ < 4; ++pt_) {                                    \
        int xi_ = (r_ + ty) * 66 + tx + pt_ * 16 + l15;                      \
        int u_ = (((xi_ << 4) + ((kcv) << 2) + lk) ^ (xi_ & 7));             \
        Bv[pt_] = *(bf16x8*)&act[u_ << 3];                                   \
      }                                                                      \
      _Pragma("unroll")                                                      \
      for (int ct_ = 0; ct_ < 4; ++ct_)                                      \
        _Pragma("unroll")                                                    \
        for (int pt_ = 0; pt_ < 4; ++pt_)                                    \
          acc[ct_][r_ * 4 + pt_] = __builtin_amdgcn_mfma_f32_16x16x32_bf16(  \
              AV[ct_], Bv[pt_], acc[ct_][r_ * 4 + pt_], 0, 0, 0);            \
    }                                                                        \
  }

  #pragma unroll 1
  for (int i = 0; i < 17; ++i) {
    int idx = i * 256 + threadIdx.x;
    if (idx < 4224) {
      int q = idx & 15, rowxz = idx >> 4;
      int xz = rowxz % 66, r = rowxz / 66;
      int yy = y0 + r - 1, xx = xz - 1;
      uint4 v = make_uint4(0, 0, 0, 0);
      if (((unsigned)yy < 64u) && ((unsigned)xx < 64u))
        v = h1g[(size_t)((b << 12) | (yy << 6) | xx) * 16 + q];
      a4[((rowxz << 4) + q) ^ (rowxz & 7)] = v;
    }
  }
  __syncthreads();

  bf16x8 AvA[4], AvB[4];
  LOADAV(AvA, wT1);
  #pragma unroll 1
  for (int tp = 0; tp < 9; ++tp) {
    int ty = tp / 3, tx = tp % 3;
    const ushort* wtp = wT1 + ((size_t)tp << 15);
    const ushort* wnx = (tp < 8) ? (wtp + (1 << 15)) : wtp;

    LOADAV(AvB, wtp + (1 << 13));  KC_BLOCK(AvA, 0);
    LOADAV(AvA, wtp + (2 << 13));  KC_BLOCK(AvB, 1);
    LOADAV(AvB, wtp + (3 << 13));  KC_BLOCK(AvA, 2);
    LOADAV(AvA, wnx);              KC_BLOCK(AvB, 3);
  }
#undef LOADAV
#undef KC_BLOCK

  #pragma unroll
  for (int ct = 0; ct < 4; ++ct)
    #pragma unroll
    for (int r = 0; r < 2; ++r)
      #pragma unroll
      for (int pt = 0; pt < 4; ++pt) {
        int x = pt * 16 + l15;
        short* ob = S1 + ((size_t)b << 20) + ((y0 + r) << 6) + x;
        #pragma unroll
        for (int j = 0; j < 4; ++j) {
          int co = co0 + ct * 16 + lk * 4 + j;
          ob[(size_t)co << 12] = (short)acc[ct][r * 4 + pt][j];
        }
      }
  #pragma unroll
  for (int ct = 0; ct < 4; ++ct) {
    float s1v[4] = {0, 0, 0, 0}, s2v[4] = {0, 0, 0, 0};
    #pragma unroll
    for (int k = 0; k < 8; ++k)
      #pragma unroll
      for (int j = 0; j < 4; ++j) {
        float v = acc[ct][k][j];
        s1v[j] += v; s2v[j] += v * v;
      }
    #pragma unroll
    for (int off = 1; off < 16; off <<= 1)
      #pragma unroll
      for (int j = 0; j < 4; ++j) {
        s1v[j] += __shfl_xor(s1v[j], off);
        s2v[j] += __shfl_xor(s2v[j], off);
      }
    if (l15 == 0) {
      #pragma unroll
      for (int j = 0; j < 4; ++j) {
        int co = co0 + ct * 16 + lk * 4 + j;
        part_s[(size_t)s * 256 + co] = s1v[j];
        part_s2[(size_t)s * 256 + co] = s2v[j];
      }
    }
  }
}

// BN2 finalize from conv1's partials
__global__ void k_bn2_fin2(const float* __restrict__ part_s, const float* __restrict__ part_s2,
                           const float* __restrict__ al1, const float* __restrict__ b1,
                           const float* __restrict__ g2, const float* __restrict__ be2,
                           const float* __restrict__ temb,
                           float* __restrict__ A, float* __restrict__ Bc, float* __restrict__ Cc) {
  int co = blockIdx.x;
  int t = threadIdx.x;
  float sS = 0.f, scS = 0.f, s2 = 0.f;
  for (int k = 0; k < 8; ++k) {
    int blk = t + k * 64;
    int b = blk >> 5;
    float c = b1[co] + temb[(b << 8) + co];
    float Sv = part_s[(size_t)blk * 256 + co];
    sS += Sv; scS += c * Sv; s2 += part_s2[(size_t)blk * 256 + co];
  }
  #pragma unroll
  for (int off = 32; off > 0; off >>= 1) {
    sS += __shfl_down(sS, off); scS += __shfl_down(scS, off); s2 += __shfl_down(s2, off);
  }
  if (t == 0) {
    float a = al1[co];
    float sumc = 0.f, sumc2 = 0.f;
    for (int b = 0; b < 16; ++b) { float c = b1[co] + temb[(b << 8) + co]; sumc += c; sumc2 += c * c; }
    float sumY = a * sS + 4096.f * sumc;
    float sumY2 = a * a * s2 + 2.f * a * scS + 4096.f * sumc2;
    const float inv = 1.f / 65536.f;
    float m = sumY * inv, var = sumY2 * inv - m * m;
    float rs = rsqrtf(var + EPS);
    float gg = rs * g2[co];
    A[co] = a * gg;
    Bc[co] = (b1[co] - m) * gg + be2[co];
    Cc[co] = gg;
  }
}

// ---------------- fallback conv1 (popcount) ----------------
__global__ __launch_bounds__(256, 1) void k_conv1(const uint4* __restrict__ sbin, const uint* __restrict__ wb1,
                                                  const int* __restrict__ base1, short* __restrict__ S1) {
  __shared__ uint wlds[32 * 36];
  __shared__ int blds[9 * 32];
  int co0 = blockIdx.y << 5;
  #pragma unroll
  for (int k = 0; k < 4; ++k) wlds[k * 256 + threadIdx.x] = wb1[co0 * 36 + k * 256 + threadIdx.x];
  if (threadIdx.x < 128) wlds[1024 + threadIdx.x] = wb1[co0 * 36 + 1024 + threadIdx.x];
  #pragma unroll
  for (int k = 0; k < 2; ++k) {
    int idx = k * 256 + threadIdx.x;
    if (idx < 288) blds[idx] = base1[(idx >> 5) * 256 + co0 + (idx & 31)];
  }
  int bt = blockIdx.x;
  int b = bt >> 4;
  int y = ((bt & 15) << 2) | (threadIdx.x >> 6);
  int cx = threadIdx.x & 63;
  uint nb[9][4];
  #pragma unroll
  for (int dy = -1; dy <= 1; ++dy)
    #pragma unroll
    for (int dx = -1; dx <= 1; ++dx) {
      int tp = (dy + 1) * 3 + (dx + 1);
      int yy = y + dy, xx = cx + dx;
      bool v = ((unsigned)yy < 64u) && ((unsigned)xx < 64u);
      uint4 q = make_uint4(0, 0, 0, 0);
      if (v) q = sbin[(b << 12) | (yy << 6) | xx];
      nb[tp][0] = q.x; nb[tp][1] = q.y; nb[tp][2] = q.z; nb[tp][3] = q.w;
    }
  int pat = ((y == 0) ? 0 : ((y == 63) ? 6 : 3)) + ((cx == 0) ? 0 : ((cx == 63) ? 2 : 1));
  __syncthreads();
  int p = (y << 6) | cx;
  short* op = S1 + ((size_t)b << 20) + ((size_t)co0 << 12) + p;
  #pragma unroll 1
  for (int cc = 0; cc < 4; ++cc) {
    short accv[8];
    #pragma unroll
    for (int j = 0; j < 8; ++j) {
      int co_l = cc * 8 + j;
      const uint4* wp4 = (const uint4*)(wlds + co_l * 36);
      uint m0 = 0, m1 = 0, m2 = 0, m3 = 0;
      #pragma unroll
      for (int tp = 0; tp < 9; ++tp) {
        uint4 w4 = wp4[tp];
        m0 += __popc(nb[tp][0] ^ w4.x);
        m1 += __popc(nb[tp][1] ^ w4.y);
        m2 += __popc(nb[tp][2] ^ w4.z);
        m3 += __popc(nb[tp][3] ^ w4.w);
      }
      accv[j] = (short)(blds[pat * 32 + co_l] - 2 * (int)((m0 + m1) + (m2 + m3)));
    }
    #pragma unroll
    for (int j = 0; j < 8; ++j) op[(size_t)(cc * 8 + j) << 12] = accv[j];
  }
}

// ---------------- fallback BN2 stats ----------------
__global__ __launch_bounds__(256) void k_bn2_part(const short* __restrict__ S1, const float* __restrict__ al1,
                                                  const float* __restrict__ b1, const float* __restrict__ temb,
                                                  float* __restrict__ part) {
  int co = blockIdx.x, chunk = blockIdx.y;
  float a = al1[co], bb = b1[co];
  float s = 0.f, s2 = 0.f;
  #pragma unroll
  for (int jb = 0; jb < 2; ++jb) {
    int b = chunk * 2 + jb;
    float tb_ = bb + temb[(b << 8) | co];
    const uint4* sp = (const uint4*)(S1 + ((size_t)b << 20) + ((size_t)co << 12));
    #pragma unroll
    for (int k = 0; k < 2; ++k) {
      uint4 q = sp[k * 256 + threadIdx.x];
      uint ws[4] = {q.x, q.y, q.z, q.w};
      #pragma unroll
      for (int w = 0; w < 4; ++w) {
        float f0 = fmaf(a, (float)((short)(ws[w] & 0xffffu)), tb_);
        float f1 = fmaf(a, (float)((short)(ws[w] >> 16)), tb_);
        s += f0 + f1;
        s2 += f0 * f0 + f1 * f1;
      }
    }
  }
  #pragma unroll
  for (int off = 32; off > 0; off >>= 1) { s += __shfl_down(s, off); s2 += __shfl_down(s2, off); }
  __shared__ float ls[4], ls2[4];
  int wid = threadIdx.x >> 6, lane = threadIdx.x & 63;
  if (lane == 0) { ls[wid] = s; ls2[wid] = s2; }
  __syncthreads();
  if (threadIdx.x == 0) {
    part[(co * 8 + chunk) * 2 + 0] = ls[0] + ls[1] + ls[2] + ls[3];
    part[(co * 8 + chunk) * 2 + 1] = ls2[0] + ls2[1] + ls2[2] + ls2[3];
  }
}

__global__ void k_bn2_fin(const float* __restrict__ part, const float* __restrict__ al1,
                          const float* __restrict__ b1, const float* __restrict__ g2,
                          const float* __restrict__ be2, float* __restrict__ A,
                          float* __restrict__ Bc, float* __restrict__ Cc) {
  int co = threadIdx.x;
  float s = 0.f, s2 = 0.f;
  for (int k = 0; k < 8; ++k) { s += part[(co * 8 + k) * 2]; s2 += part[(co * 8 + k) * 2 + 1]; }
  const float inv = 1.f / 65536.f;
  float m = s * inv, var = s2 * inv - m * m;
  float rs = rsqrtf(var + EPS);
  float gg = rs * g2[co];
  A[co] = al1[co] * gg;
  Bc[co] = (b1[co] - m) * gg + be2[co];
  Cc[co] = gg;
}

// ---------------- binarize2 -> bf16 +-1, layout [b][px][256ci] ----------------
__global__ __launch_bounds__(256) void k_bin2_bf16(const short* __restrict__ S1, const float* __restrict__ A,
                                                   const float* __restrict__ Bc, const float* __restrict__ Cc,
                                                   const float* __restrict__ temb, uint4* __restrict__ h2u4) {
  __shared__ uint4 tile[64 * 32];
  int b = blockIdx.x >> 6;
  int px0 = (blockIdx.x & 63) << 6;
  int pxl = threadIdx.x & 63, quad = threadIdx.x >> 6;
  const short* sp = S1 + ((size_t)b << 20) + (px0 + pxl);
  const float* tp = temb + (b << 8);
  #pragma unroll 1
  for (int g = 0; g < 8; ++g) {
    uint d[4];
    #pragma unroll
    for (int h = 0; h < 4; ++h) {
      int c0 = quad * 64 + g * 8 + h * 2;
      float v0 = A[c0] * (float)sp[(size_t)c0 << 12] + Bc[c0] + Cc[c0] * tp[c0];
      float v1 = A[c0 + 1] * (float)sp[(size_t)(c0 + 1) << 12] + Bc[c0 + 1] + Cc[c0 + 1] * tp[c0 + 1];
      uint s0 = (v0 > 0.f) ? 0x3F80u : 0xBF80u;
      uint s1 = (v1 > 0.f) ? 0x3F80u : 0xBF80u;
      d[h] = s0 | (s1 << 16);
    }
    int slot = quad * 8 + g;
    tile[pxl * 32 + (slot ^ (pxl & 7))] = make_uint4(d[0], d[1], d[2], d[3]);
  }
  __syncthreads();
  uint4* dst = h2u4 + ((size_t)(b << 12) + px0) * 32;
  #pragma unroll
  for (int k = 0; k < 8; ++k) {
    int c = k * 256 + threadIdx.x;
    int px = c >> 5, slot = c & 31;
    dst[c] = tile[px * 32 + (slot ^ (px & 7))];
  }
}

// ---------------- conv2 MFMA v5 (R10-proven) ----------------
__global__ __launch_bounds__(256, 2) void k_conv2_mfma(const ushort* __restrict__ h2,
                                                       const ushort* __restrict__ wT,
                                                       const float* __restrict__ al2,
                                                       float* __restrict__ out) {
  __shared__ ushort act[4 * 66 * 128];
  int bidx = blockIdx.x;
  int s = (bidx & 7) * 64 + (bidx >> 3);
  int b = s >> 5, y0 = (s & 31) << 1;
  int lane = threadIdx.x & 63, wave = threadIdx.x >> 6;
  int co0 = wave << 6;
  int l15 = lane & 15, lk = lane >> 4;

  f32x4 acc[4][8] = {};
  const uint4* h2g = (const uint4*)h2;
  uint4* a4 = (uint4*)act;
  const size_t abase = (size_t)((co0 + l15) << 5) + (lk << 3);

#define LOADAV(dst, ptr)                                                     \
  {                                                                          \
    _Pragma("unroll")                                                        \
    for (int ct_ = 0; ct_ < 4; ++ct_)                                        \
      dst[ct_] = *(const bf16x8*)((ptr) + abase + (ct_ << 9));               \
  }
#define KC_BLOCK(AV, kcv)                                                    \
  {                                                                          \
    _Pragma("unroll")                                                        \
    for (int r_ = 0; r_ < 2; ++r_) {                                         \
      bf16x8 Bv[4];                                                          \
      _Pragma("unroll")                                                      \
      for (int pt_ = 0; pt_ < 4; ++pt_) {                                    \
        int xi_ = (r_ + ty) * 66 + tx + pt_ * 16 + l15;                      \
        int u_ = (((xi_ << 4) + ((kcv) << 2) + lk) ^ (xi_ & 7));             \
        Bv[pt_] = *(bf16x8*)&act[u_ << 3];                                   \
      }                                                                      \
      _Pragma("unroll")                                                      \
      for (int ct_ = 0; ct_ < 4; ++ct_)                                      \
        _Pragma("unroll")                                                    \
        for (int pt_ = 0; pt_ < 4; ++pt_)                                    \
          acc[ct_][r_ * 4 + pt_] = __builtin_amdgcn_mfma_f32_16x16x32_bf16(  \
              AV[ct_], Bv[pt_], acc[ct_][r_ * 4 + pt_], 0, 0, 0);            \
    }                                                                        \
  }

  #pragma unroll 1
  for (int chunk = 0; chunk < 2; ++chunk) {
    if (chunk) __syncthreads();
    #pragma unroll 1
    for (int i = 0; i < 17; ++i) {
      int idx = i * 256 + threadIdx.x;
      if (idx < 4224) {
        int q = idx & 15, rowxz = idx >> 4;
        int xz = rowxz % 66, r = rowxz / 66;
        int yy = y0 + r - 1, xx = xz - 1;
        uint4 v = make_uint4(0, 0, 0, 0);
        if (((unsigned)yy < 64u) && ((unsigned)xx < 64u))
          v = h2g[(size_t)((b << 12) | (yy << 6) | xx) * 32 + chunk * 16 + q];
        a4[((rowxz << 4) + q) ^ (rowxz & 7)] = v;
      }
    }
    __syncthreads();

    const ushort* wch = wT + ((size_t)chunk << 15);
    bf16x8 AvA[4], AvB[4];
    LOADAV(AvA, wch);

    #pragma unroll 1
    for (int tp = 0; tp < 9; ++tp) {
      int ty = tp / 3, tx = tp % 3;
      const ushort* wtp = wch + ((size_t)tp << 16);
      const ushort* wnx = (tp < 8) ? (wtp + (1 << 16)) : wtp;

      LOADAV(AvB, wtp + (1 << 13));  KC_BLOCK(AvA, 0);
      LOADAV(AvA, wtp + (2 << 13));  KC_BLOCK(AvB, 1);
      LOADAV(AvB, wtp + (3 << 13));  KC_BLOCK(AvA, 2);
      LOADAV(AvA, wnx);              KC_BLOCK(AvB, 3);
    }
  }
#undef LOADAV
#undef KC_BLOCK

  #pragma unroll
  for (int ct = 0; ct < 4; ++ct) {
    #pragma unroll
    for (int r = 0; r < 2; ++r) {
      #pragma unroll
      for (int pt = 0; pt < 4; ++pt) {
        int x = pt * 16 + l15;
        float* ob = out + ((size_t)b << 20) + ((y0 + r) << 6) + x;
        #pragma unroll
        for (int j = 0; j < 4; ++j) {
          int co = co0 + ct * 16 + lk * 4 + j;
          float* p = ob + ((size_t)co << 12);
          *p = fmaf(al2[co], acc[ct][r * 4 + pt][j], *p);
        }
      }
    }
  }
}

// ---------------- fallback conv2 path ----------------
__global__ __launch_bounds__(256) void k_bin2_packed(const short* __restrict__ S1, const float* __restrict__ A,
                                                     const float* __restrict__ Bc, const float* __restrict__ Cc,
                                                     const float* __restrict__ temb, uint4* __restrict__ hbin) {
  int pg = blockIdx.x * 256 + threadIdx.x;
  int b = pg >> 12, p = pg & 4095;
  int c0 = blockIdx.y << 7;
  const short* sp = S1 + ((size_t)b << 20) + p;
  const float* tp = temb + (b << 8);
  uint w[4];
  #pragma unroll
  for (int wd = 0; wd < 4; ++wd) {
    uint acc = 0;
    #pragma unroll
    for (int i = 0; i < 32; ++i) {
      int co = c0 + wd * 32 + i;
      float v = A[co] * (float)sp[(size_t)co << 12] + Bc[co] + Cc[co] * tp[co];
      acc |= (v > 0.f ? 1u : 0u) << i;
    }
    w[wd] = acc;
  }
  hbin[pg * 2 + blockIdx.y] = make_uint4(w[0], w[1], w[2], w[3]);
}

__global__ __launch_bounds__(256, 1) void k_conv2_pop(const uint4* __restrict__ hbin, const uint* __restrict__ wb2,
                                                      const int* __restrict__ base2, const float* __restrict__ al2,
                                                      float* __restrict__ out) {
  __shared__ uint wlds[32 * 72];
  __shared__ int blds[9 * 32];
  int co0 = blockIdx.y << 5;
  #pragma unroll
  for (int k = 0; k < 9; ++k) wlds[k * 256 + threadIdx.x] = wb2[co0 * 72 + k * 256 + threadIdx.x];
  #pragma unroll
  for (int k = 0; k < 2; ++k) {
    int idx = k * 256 + threadIdx.x;
    if (idx < 288) blds[idx] = base2[(idx >> 5) * 256 + co0 + (idx & 31)];
  }
  int bt = blockIdx.x;
  int b = bt >> 4;
  int y = ((bt & 15) << 2) | (threadIdx.x >> 6);
  int cx = threadIdx.x & 63;
  uint nb[9][8];
  #pragma unroll
  for (int dy = -1; dy <= 1; ++dy)
    #pragma unroll
    for (int dx = -1; dx <= 1; ++dx) {
      int tp = (dy + 1) * 3 + (dx + 1);
      int yy = y + dy, xx = cx + dx;
      bool v = ((unsigned)yy < 64u) && ((unsigned)xx < 64u);
      uint4 q0 = make_uint4(0, 0, 0, 0), q1 = make_uint4(0, 0, 0, 0);
      if (v) {
        int pix = (b << 12) | (yy << 6) | xx;
        q0 = hbin[pix * 2 + 0];
        q1 = hbin[pix * 2 + 1];
      }
      nb[tp][0] = q0.x; nb[tp][1] = q0.y; nb[tp][2] = q0.z; nb[tp][3] = q0.w;
      nb[tp][4] = q1.x; nb[tp][5] = q1.y; nb[tp][6] = q1.z; nb[tp][7] = q1.w;
    }
  int pat = ((y == 0) ? 0 : ((y == 63) ? 6 : 3)) + ((cx == 0) ? 0 : ((cx == 63) ? 2 : 1));
  __syncthreads();
  int p = (y << 6) | cx;
  float* op = out + ((size_t)b << 20) + ((size_t)co0 << 12) + p;
  #pragma unroll 1
  for (int cc = 0; cc < 4; ++cc) {
    float ov[8];
    #pragma unroll
    for (int j = 0; j < 8; ++j) ov[j] = op[(size_t)(cc * 8 + j) << 12];
    #pragma unroll
    for (int j = 0; j < 8; ++j) {
      int co_l = cc * 8 + j;
      const uint4* wp4 = (const uint4*)(wlds + co_l * 72);
      uint m0 = 0, m1 = 0, m2 = 0, m3 = 0;
      #pragma unroll
      for (int tp = 0; tp < 9; ++tp) {
        uint4 wa = wp4[tp * 2 + 0];
        uint4 wb_ = wp4[tp * 2 + 1];
        m0 += __popc(nb[tp][0] ^ wa.x);
        m1 += __popc(nb[tp][1] ^ wa.y);
        m2 += __popc(nb[tp][2] ^ wa.z);
        m3 += __popc(nb[tp][3] ^ wa.w);
        m0 += __popc(nb[tp][4] ^ wb_.x);
        m1 += __popc(nb[tp][5] ^ wb_.y);
        m2 += __popc(nb[tp][6] ^ wb_.z);
        m3 += __popc(nb[tp][7] ^ wb_.w);
      }
      int acc = blds[pat * 32 + co_l] - 2 * (int)((m0 + m1) + (m2 + m3));
      ov[j] = fmaf(al2[co0 + co_l], (float)acc, ov[j]);
    }
    #pragma unroll
    for (int j = 0; j < 8; ++j) op[(size_t)(cc * 8 + j) << 12] = ov[j];
  }
}

extern "C" void kernel_launch(void* const* d_in, const int* in_sizes, int n_in,
                              void* d_out, int out_size, void* d_ws, size_t ws_size,
                              hipStream_t stream) {
  const float* x    = (const float*)d_in[0];
  const float* t    = (const float*)d_in[1];
  const float* bn1g = (const float*)d_in[2];
  const float* bn1b = (const float*)d_in[3];
  const float* w1   = (const float*)d_in[4];
  const float* b1   = (const float*)d_in[5];
  const float* tW   = (const float*)d_in[6];
  const float* tb   = (const float*)d_in[7];
  const float* bn2g = (const float*)d_in[8];
  const float* bn2b = (const float*)d_in[9];
  const float* w2   = (const float*)d_in[10];
  const float* b2   = (const float*)d_in[11];
  const float* wsk  = (const float*)d_in[12];
  const float* bsk  = (const float*)d_in[13];
  float* out = (float*)d_out;
  char* ws = (char*)d_ws;

  float* bn1part = (float*)(ws + 0);
  float* sc1     = (float*)(ws + 8192);
  float* sh1     = (float*)(ws + 8704);
  uint4* sbin    = (uint4*)(ws + 9216);      // 1 MB (fallback bin1)
  uint*  wb1     = (uint*) (ws + 1057792);
  float* al1     = (float*)(ws + 1094656);
  uint*  wb2     = (uint*) (ws + 1095680);
  float* al2     = (float*)(ws + 1169408);
  float* swkT    = (float*)(ws + 1170432);
  float* temb    = (float*)(ws + 1301504);
  float* bn2part = (float*)(ws + 1317888);
  float* A2      = (float*)(ws + 1334272);
  float* Bc2     = (float*)(ws + 1335296);
  float* Cc2     = (float*)(ws + 1336320);
  int*   base1g  = (int*)  (ws + 1337344);
  int*   base2g  = (int*)  (ws + 1346560);
  uint4*  hbin    = (uint4*)(ws + 1355776);  // 2 MB (fallback conv2)
  float*  part_s  = (float*)(ws + 1355776);  // 512 KB (mfma path)
  float*  part_s2 = (float*)(ws + 1880064);  // 512 KB
  ushort* wT1     = (ushort*)(ws + 2404352); // 590 KB
  ushort* wT2     = (ushort*)(ws + 3452928); // 1.18 MB
  short*  S1      = (short*)(ws + 4632576);  // 33.5 MB
  ushort* h2      = (ushort*)(ws + 38187008);// 33.5 MB
  ushort* h1      = (ushort*)(ws + 71741440);// 16.8 MB -> end 88518656
  const size_t WS_NEED2 = 71741440ULL;
  const size_t WS_NEED1 = 88518656ULL;
  bool mode2 = (ws_size >= WS_NEED2);
  bool mode1 = (ws_size >= WS_NEED1);

  k_bn1_part<<<dim3(128, 8), 256, 0, stream>>>(x, bn1part);
  k_bn1_fin<<<1, 128, 0, stream>>>(bn1part, bn1g, bn1b, sc1, sh1);
  k_packw1<<<256, 128, 0, stream>>>(w1, wb1, al1, wT1);
  k_packw2<<<256, 256, 0, stream>>>(w2, wb2, al2, wT2);
  k_base<<<1, 256, 0, stream>>>(wb1, wb2, base1g, base2g);
  k_packws<<<256, 128, 0, stream>>>(wsk, swkT);
  k_temb<<<16, 256, 0, stream>>>(t, tW, tb, temb);
  k_skip<<<dim3(512, 2), 256, 0, stream>>>(x, swkT, bsk, b2, sc1, sh1, (uint*)sbin, h1,
                                           mode1 ? 1 : 0, out);
  if (mode1) {
    k_conv1_mfma<<<512, 256, 0, stream>>>(h1, wT1, S1, part_s, part_s2);
    k_bn2_fin2<<<256, 64, 0, stream>>>(part_s, part_s2, al1, b1, bn2g, bn2b, temb, A2, Bc2, Cc2);
  } else {
    k_conv1<<<dim3(256, 8), 256, 0, stream>>>(sbin, wb1, base1g, S1);
    k_bn2_part<<<dim3(256, 8), 256, 0, stream>>>(S1, al1, b1, temb, bn2part);
    k_bn2_fin<<<1, 256, 0, stream>>>(bn2part, al1, b1, bn2g, bn2b, A2, Bc2, Cc2);
  }
  if (mode2) {
    k_bin2_bf16<<<1024, 256, 0, stream>>>(S1, A2, Bc2, Cc2, temb, (uint4*)h2);
    k_conv2_mfma<<<512, 256, 0, stream>>>(h2, wT2, al2, out);
  } else {
    k_bin2_packed<<<dim3(256, 2), 256, 0, stream>>>(S1, A2, Bc2, Cc2, temb, hbin);
    k_conv2_pop<<<dim3(256, 8), 256, 0, stream>>>(hbin, wb2, base2g, al2, out);
  }
}